// Round 11
// baseline (509.174 us; speedup 1.0000x reference)
//
#include <hip/hip_runtime.h>

typedef __attribute__((ext_vector_type(4))) float f32x4;
typedef __attribute__((ext_vector_type(8))) short bf16x8;

#define MFMA16(a, b, c) __builtin_amdgcn_mfma_f32_16x16x32_bf16((a), (b), (c), 0, 0, 0)
#define LOG2E 1.44269504088896340736f

static __device__ __forceinline__ float bf2f(short u) {
  unsigned x = ((unsigned)(unsigned short)u) << 16;
  return __builtin_bit_cast(float, x);
}
static __device__ __forceinline__ short f2bf(float f) {
  unsigned u = __builtin_bit_cast(unsigned, f);
  u += 0x7fffu + ((u >> 16) & 1u);
  return (short)(u >> 16);
}
// global -> LDS direct DMA, 16B per lane (guide §5); source pre-swizzled.
static __device__ __forceinline__ void gll16(const void* g, void* l) {
  __builtin_amdgcn_global_load_lds(
      (const __attribute__((address_space(1))) unsigned*)(unsigned long long)g,
      (__attribute__((address_space(3))) unsigned*)(unsigned)(unsigned long long)l,
      16, 0, 0);
}

// ------- merged f32 -> bf16 conversion: h, Wq, Wk, Wv in one launch --------
__global__ void __launch_bounds__(256) cvt4(const float* __restrict__ h,
                                            const float* __restrict__ wq,
                                            const float* __restrict__ wk,
                                            const float* __restrict__ wv,
                                            short* __restrict__ hbf,
                                            short* __restrict__ wall) {
  const long long C0 = 917504, C1 = 1605632, C2 = 229376;  // 8-elem chunks
  long long ch = (long long)blockIdx.x * 256 + threadIdx.x;
  const long long stride = (long long)gridDim.x * 256;
  const long long total = C0 + C1 + 2 * C2;
  for (; ch < total; ch += stride) {
    const float* s;
    short* d;
    long long off;
    if (ch < C0) { s = h; d = hbf; off = ch; }
    else if (ch < C0 + C1) { s = wq; d = wall; off = ch - C0; }
    else if (ch < C0 + C1 + C2) { s = wk; d = wall + (size_t)3584 * 3584; off = ch - C0 - C1; }
    else { s = wv; d = wall + (size_t)4096 * 3584; off = ch - C0 - C1 - C2; }
    const long long i = off * 8;
    f32x4 a = *(const f32x4*)(s + i);
    f32x4 b = *(const f32x4*)(s + i + 4);
    bf16x8 o;
    o[0] = f2bf(a[0]); o[1] = f2bf(a[1]); o[2] = f2bf(a[2]); o[3] = f2bf(a[3]);
    o[4] = f2bf(b[0]); o[5] = f2bf(b[1]); o[6] = f2bf(b[2]); o[7] = f2bf(b[3]);
    *(bf16x8*)(d + i) = o;
  }
}

__global__ void __launch_bounds__(256) cvt_kernel(const float* __restrict__ src,
                                                  short* __restrict__ dst,
                                                  long long n) {
  long long i = ((long long)blockIdx.x * 256 + threadIdx.x) * 8;
  const long long stride = (long long)gridDim.x * 256 * 8;
  for (; i < n; i += stride) {
    f32x4 a = *(const f32x4*)(src + i);
    f32x4 b = *(const f32x4*)(src + i + 4);
    bf16x8 o;
    o[0] = f2bf(a[0]); o[1] = f2bf(a[1]); o[2] = f2bf(a[2]); o[3] = f2bf(a[3]);
    o[4] = f2bf(b[0]); o[5] = f2bf(b[1]); o[6] = f2bf(b[2]); o[7] = f2bf(b[3]);
    *(bf16x8*)(dst + i) = o;
  }
}

// ---------------- RoPE cos/sin table: [2048][64] ----------------
__global__ void rope_table(const int* __restrict__ pos, float* __restrict__ ctab,
                           float* __restrict__ stab) {
  const int s = blockIdx.x;
  const int i = threadIdx.x;  // 0..63
  const float p = (float)pos[s];
  const float ang = p * exp2f(-(float)i * 0.3114307588956902f);
  ctab[s * 64 + i] = cosf(ang);
  stab[s * 64 + i] = sinf(ang);
}

// ---- stream-K partial gathers. 1x18 rects: xcd = tr (M-tile row), rt = tc.
// QKV: 36 units/block, tile = 56 units. Tile tc's contributors: j in
// [56tc/36, (56tc+55)/36]; seg = 0 iff tc is block j's FIRST tile.
// Slots row-major 256x256 bf16 at Pp[(xcd*28+j)*2+seg].
static __device__ __forceinline__ void qkv_gather(const short* __restrict__ Pp,
                                                  int tr, int tc, int s, int col0,
                                                  float* x, float* y) {
  const int j0 = (56 * tc) / 36, j1 = (56 * tc + 55) / 36;
  const size_t off = (size_t)(s & 255) * 256 + (col0 & 255);
#pragma unroll 1
  for (int j = j0; j <= j1; ++j) {
    const int seg = ((36 * j) / 56 == tc) ? 0 : 1;
    const short* p = Pp + ((size_t)((tr * 28 + j) * 2 + seg)) * 65536 + off;
    const bf16x8 lo = *(const bf16x8*)p;
    const bf16x8 hi = *(const bf16x8*)(p + 64);
#pragma unroll
    for (int q = 0; q < 8; ++q) { x[q] += bf2f(lo[q]); y[q] += bf2f(hi[q]); }
  }
}
static __device__ __forceinline__ void qkv_gather8(const short* __restrict__ Pp,
                                                   int tr, int tc, int s, int col0,
                                                   float* x) {
  const int j0 = (56 * tc) / 36, j1 = (56 * tc + 55) / 36;
  const size_t off = (size_t)(s & 255) * 256 + (col0 & 255);
#pragma unroll 1
  for (int j = j0; j <= j1; ++j) {
    const int seg = ((36 * j) / 56 == tc) ? 0 : 1;
    const short* p = Pp + ((size_t)((tr * 28 + j) * 2 + seg)) * 65536 + off;
    const bf16x8 lo = *(const bf16x8*)p;
#pragma unroll
    for (int q = 0; q < 8; ++q) x[q] += bf2f(lo[q]);
  }
}

// RoPE from QKV partials + bias -> bf16 qkvp (q,k regions). Q heads (h<28)
// pre-scaled by SCALE*LOG2E (exp2-domain scores).
__global__ void __launch_bounds__(256) rope_apply5(const short* __restrict__ Pp,
                                                   const float* __restrict__ bq,
                                                   const float* __restrict__ bk,
                                                   const float* __restrict__ ctab,
                                                   const float* __restrict__ stab,
                                                   short* __restrict__ qkvp) {
  const int idx = blockIdx.x * 256 + threadIdx.x;  // 2048*32*8
  const int c = idx & 7;
  const int h = (idx >> 3) & 31;
  const int s = idx >> 8;
  const int col0 = h * 128 + c * 8;  // < 4096; col0%256 <= 184, +64 stays in tile
  float x[8] = {}, y[8] = {};
  qkv_gather(Pp, s >> 8, col0 >> 8, s, col0, x, y);
  const float qs = (h < 28) ? (0.08838834764831845f * LOG2E) : 1.0f;
  const float* bl = (h < 28) ? (bq + col0) : (bk + col0 - 3584);
  const float* cp = ctab + s * 64 + c * 8;
  const float* sp = stab + s * 64 + c * 8;
  bf16x8 lo2, hi2;
#pragma unroll
  for (int j = 0; j < 8; ++j) {
    const float xv = x[j] + bl[j], yv = y[j] + bl[j + 64];
    const float cv = cp[j], sv = sp[j];
    lo2[j] = f2bf((xv * cv - yv * sv) * qs);
    hi2[j] = f2bf((yv * cv + xv * sv) * qs);
  }
  short* dst = qkvp + (size_t)s * 4608 + col0;
  *(bf16x8*)dst = lo2;
  *(bf16x8*)(dst + 64) = hi2;
}

// V region from partials + bias -> V^T bf16 [4][128][2048]
__global__ void __launch_bounds__(256) v_transpose5(const short* __restrict__ Pp,
                                                    const float* __restrict__ bv,
                                                    short* __restrict__ vtb) {
  __shared__ short t[64 * 48];
  const int dt = blockIdx.x, st = blockIdx.y, kv = blockIdx.z;
  const int tid = threadIdx.x;
  {
    const int r = tid >> 2, c8 = tid & 3;
    const int s = st * 64 + r;
    const int col0 = 4096 + kv * 128 + dt * 32 + c8 * 8;
    float x[8] = {};
    qkv_gather8(Pp, s >> 8, col0 >> 8, s, col0, x);
    const float* bp = bv + kv * 128 + dt * 32 + c8 * 8;
#pragma unroll
    for (int j = 0; j < 8; ++j) t[r * 48 + c8 * 8 + j] = f2bf(x[j] + bp[j]);
  }
  __syncthreads();
  {
    const int d = tid >> 3, c = tid & 7;
    bf16x8 v;
#pragma unroll
    for (int i = 0; i < 8; ++i) v[i] = t[(c * 8 + i) * 48 + d];
    *(bf16x8*)(vtb + ((size_t)kv * 128 + dt * 32 + d) * 2048 + st * 64 + c * 8) = v;
  }
}

// O-proj reduce: out = blocks 2tc, 2tc+1 (both seg 0), f32.
__global__ void __launch_bounds__(256) o_reduce3(const short* __restrict__ Pp,
                                                 float* __restrict__ out) {
  const int idx = blockIdx.x * 256 + threadIdx.x;  // 2048*448
  const int s = idx / 448;
  const int col0 = (idx % 448) * 8;
  const int tr = s >> 8, tc = col0 >> 8;  // tc 0..13
  const size_t off = (size_t)(s & 255) * 256 + (col0 & 255);
  const short* pA = Pp + ((size_t)((tr * 28 + 2 * tc) * 2)) * 65536 + off;
  const short* pB = Pp + ((size_t)((tr * 28 + 2 * tc + 1) * 2)) * 65536 + off;
  const bf16x8 a = *(const bf16x8*)pA;
  const bf16x8 b = *(const bf16x8*)pB;
  f32x4 o1, o2;
#pragma unroll
  for (int q = 0; q < 4; ++q) {
    o1[q] = bf2f(a[q]) + bf2f(b[q]);
    o2[q] = bf2f(a[q + 4]) + bf2f(b[q + 4]);
  }
  float* dst = out + (size_t)s * 3584 + col0;
  *(f32x4*)dst = o1;
  *(f32x4*)(dst + 4) = o2;
}

// ---- stream-K 8-phase bf16 GEMM, 1x18 XCD rect (A panel L2-resident) ------
// A[2048,K]*B[N,K]^T. 224 blocks: xcd=bid&7 owns M-tile-row xcd -> the
// block's A panel (256 rows x K, 1.8 MB) is FIXED and L2-resident; only B
// streams (via L3). In-rect units u=(tc,kt)=(u/56,u%56); block jj=bid>>3
// owns [UNITS*jj, UNITS*jj+UNITS). Phase/sync/vmcnt engine identical to r7
// (ledger-verified). Epilogue: row-major bf16 partial tiles (r9-verified).
// Boundary parity even -> mid-epilogue only at post-P8. Stores inflate
// vmcnt -> later counted waits only get stronger.
template <int UNITS>
__global__ void __launch_bounds__(512, 2)
gemm_sk3(const short* __restrict__ A, const short* __restrict__ B,
         short* __restrict__ Pp, int K) {
  __shared__ short As[2][256 * 64];
  __shared__ short Bs[2][256 * 64];
  const int bid = (int)blockIdx.x;
  const int xcd = bid & 7, jj = bid >> 3;
  const int u0 = jj * UNITS;
  const int T0 = u0 / 56;
  const int Tend = (u0 + UNITS - 1) / 56;
  const int kb1 = 56 * (T0 + 1);
  const int tm = xcd << 8;
  const int tid = (int)threadIdx.x;
  const int wave = tid >> 6, lane = tid & 63;
  const int l15 = lane & 15, g = lane >> 4;
  const int wm = wave >> 2, wn = wave & 3;

  f32x4 acc[2][4][2][2] = {};  // [rh][mq][ch][nq]
  bf16x8 af[4][2], b0[2][2], b1[2][2];

#define STG_A(b, uu, h)                                                         \
  { const int kt_ = (uu) % 56;                                                  \
    _Pragma("unroll") for (int jq = 0; jq < 2; ++jq) {                          \
      const int lr = (h) * 128 + jq * 64 + (tid >> 3);                          \
      const int wmm = (lr >> 6) & 1;                                            \
      const int rr = lr & 63;                                                   \
      const int grow = wmm * 128 + (h) * 64 + rr;                               \
      const int sc = (tid & 7) ^ (rr & 7);                                      \
      gll16(A + (size_t)(tm + grow) * K + (size_t)kt_ * 64 + sc * 8,            \
            &As[b][((h) * 128 + jq * 64 + wave * 8) * 64]);                     \
    } }
#define STG_B(b, uu, h)                                                         \
  { const int tc_ = (uu) / 56, kt_ = (uu)-tc_ * 56;                             \
    const int tn_ = tc_ << 8;                                                   \
    _Pragma("unroll") for (int jq = 0; jq < 2; ++jq) {                          \
      const int lr = (h) * 128 + jq * 64 + (tid >> 3);                          \
      const int wnn = (lr >> 5) & 3;                                            \
      const int rr = lr & 31;                                                   \
      const int gcol = wnn * 64 + (h) * 32 + rr;                                \
      const int sc = (tid & 7) ^ (rr & 7);                                      \
      gll16(B + (size_t)(tn_ + gcol) * K + (size_t)kt_ * 64 + sc * 8,           \
            &Bs[b][((h) * 128 + jq * 64 + wave * 8) * 64]);                     \
    } }
#define LDA(buf, rh)                                                            \
  { _Pragma("unroll") for (int mq = 0; mq < 4; ++mq)                            \
      _Pragma("unroll") for (int ks = 0; ks < 2; ++ks) {                        \
        const int lr = (rh) * 128 + wm * 64 + mq * 16 + l15;                    \
        af[mq][ks] =                                                            \
            *(const bf16x8*)(&As[buf][lr * 64 + (((ks * 4 + g) ^ (lr & 7)) * 8)]); \
      } }
#define LDB(buf, ch, ARR)                                                       \
  { _Pragma("unroll") for (int nq = 0; nq < 2; ++nq)                            \
      _Pragma("unroll") for (int ks = 0; ks < 2; ++ks) {                        \
        const int lr = (ch) * 128 + wn * 32 + nq * 16 + l15;                    \
        ARR[nq][ks] =                                                           \
            *(const bf16x8*)(&Bs[buf][lr * 64 + (((ks * 4 + g) ^ (lr & 7)) * 8)]); \
      } }
#define VMW() { asm volatile("s_waitcnt vmcnt(4)" ::: "memory"); }
#define PH(RH, CH, BARR, TAILBLK)                                               \
  {                                                                             \
    __builtin_amdgcn_s_barrier();                                               \
    asm volatile("s_waitcnt lgkmcnt(0)" ::: "memory");                          \
    __builtin_amdgcn_sched_barrier(0);                                          \
    __builtin_amdgcn_s_setprio(1);                                              \
    _Pragma("unroll") for (int mq = 0; mq < 4; ++mq)                            \
      _Pragma("unroll") for (int nq = 0; nq < 2; ++nq) {                        \
        acc[RH][mq][CH][nq] = MFMA16(af[mq][0], BARR[nq][0], acc[RH][mq][CH][nq]); \
        acc[RH][mq][CH][nq] = MFMA16(af[mq][1], BARR[nq][1], acc[RH][mq][CH][nq]); \
      }                                                                         \
    __builtin_amdgcn_s_setprio(0);                                              \
    TAILBLK;                                                                    \
    __builtin_amdgcn_sched_barrier(0);                                          \
  }
#define PEPI(seg)                                                               \
  { short* pb = Pp + ((size_t)(((xcd * 28 + jj) << 1) + (seg))) * 65536;        \
    _Pragma("unroll") for (int rh = 0; rh < 2; ++rh)                            \
    _Pragma("unroll") for (int mq = 0; mq < 4; ++mq)                            \
    _Pragma("unroll") for (int ch = 0; ch < 2; ++ch)                            \
    _Pragma("unroll") for (int nq = 0; nq < 2; ++nq) {                          \
      const int colL = wn * 64 + ch * 32 + nq * 16 + l15;                       \
      const int rowL = wm * 128 + rh * 64 + mq * 16 + g * 4;                    \
      _Pragma("unroll") for (int r = 0; r < 4; ++r)                             \
        pb[(rowL + r) * 256 + colL] = f2bf(acc[rh][mq][ch][nq][r]);             \
    } }
#define RSTACC()                                                                \
  { _Pragma("unroll") for (int rh = 0; rh < 2; ++rh)                            \
    _Pragma("unroll") for (int mq = 0; mq < 4; ++mq)                            \
    _Pragma("unroll") for (int ch = 0; ch < 2; ++ch)                            \
    _Pragma("unroll") for (int nq = 0; nq < 2; ++nq)                            \
      acc[rh][mq][ch][nq] = f32x4{0.f, 0.f, 0.f, 0.f}; }

  // prologue: stage units u0 (buf0), u0+1 (buf1); drain u0; read P1 frags.
  STG_A(0, u0, 0); STG_A(0, u0, 1); STG_B(0, u0, 0); STG_B(0, u0, 1);
  STG_A(1, u0 + 1, 0); STG_A(1, u0 + 1, 1); STG_B(1, u0 + 1, 0); STG_B(1, u0 + 1, 1);
  asm volatile("s_waitcnt vmcnt(8)" ::: "memory");
  __builtin_amdgcn_s_barrier();
  LDA(0, 0); LDB(0, 0, b0);

#pragma unroll 1
  for (int i = 0; i < UNITS / 2; ++i) {
    const int uu2 = u0 + 2 * i + 2, uu3 = uu2 + 1;
    const bool more = (i < UNITS / 2 - 1);
    PH(0, 0, b0, { LDB(0, 1, b1); });
    PH(0, 1, b1, { if (more) STG_A(0, uu2, 0); LDA(0, 1); });
    PH(1, 1, b1, { if (more) { STG_B(0, uu2, 1); VMW(); }
                   else { asm volatile("s_waitcnt vmcnt(0)" ::: "memory"); } });
    PH(1, 0, b0, { if (more) { STG_A(0, uu2, 1); STG_B(0, uu2, 0); }
                   LDA(1, 0); LDB(1, 0, b0); });
    PH(0, 0, b0, { LDB(1, 1, b1); });
    PH(0, 1, b1, { if (more) STG_A(1, uu3, 0); LDA(1, 1); });
    PH(1, 1, b1, { if (more) { STG_B(1, uu3, 1); VMW(); } });
    PH(1, 0, b0, { if (more) { STG_A(1, uu3, 1); STG_B(1, uu3, 0);
                               LDA(0, 0); LDB(0, 0, b0); } });
    // tile boundary (even parity -> only possible here); never on last iter.
    if (Tend > T0 && (u0 + 2 * i + 2 == kb1)) { PEPI(0); RSTACC(); }
  }
  PEPI((Tend > T0) ? 1 : 0);
#undef STG_A
#undef STG_B
#undef LDA
#undef LDB
#undef VMW
#undef PH
#undef PEPI
#undef RSTACC
}

// ---------------- flash attention, 2-phase pipelined, paired q-tiles --------
__global__ void __launch_bounds__(256) attn_kernel(const short* __restrict__ qkv,
                                                   const short* __restrict__ vtb,
                                                   short* __restrict__ outb) {
  const int lid = (int)blockIdx.x + ((int)blockIdx.y << 4);
  const int kvh = (lid & 7) >> 1;
  const int u = ((lid >> 3) << 1) + (lid & 1);  // 0..111 within kv group
  const int head = kvh * 7 + (u >> 4);
  const int qtA = u & 15, qtB = 31 - qtA;

  const int tid = threadIdx.x;
  const int lane = tid & 63, wave = tid >> 6;
  const int l15 = lane & 15, g = lane >> 4;

  __shared__ short Ks[2][64 * 128];
  __shared__ short Vs[2][128 * 64];
  __shared__ short Ps[4][16 * 64];

  const short* kbase = qkv + 3584 + kvh * 128;
  const short* vbase = vtb + (size_t)kvh * 128 * 2048;
  const float NINF = -__builtin_inff();

  bf16x8 qf[4];
  f32x4 o[8];
  float mrun[4], lrun[4];

#define LOADQ(qt)                                                                  \
  {                                                                                \
    const short* qptr =                                                            \
        qkv + (size_t)((qt)*64 + wave * 16 + l15) * 4608 + head * 128 + g * 8;     \
    _Pragma("unroll") for (int ds = 0; ds < 4; ++ds) qf[ds] =                      \
        *(const bf16x8*)(qptr + ds * 32);                                          \
  }
#define RESET()                                                                    \
  {                                                                                \
    _Pragma("unroll") for (int nd = 0; nd < 8; ++nd) o[nd] = f32x4{0.f,0.f,0.f,0.f}; \
    _Pragma("unroll") for (int r = 0; r < 4; ++r) { mrun[r] = NINF; lrun[r] = 0.f; } \
  }
#define STAGE(kv, b)                                                               \
  {                                                                                \
    _Pragma("unroll") for (int it = 0; it < 4; ++it) {                             \
      const int chunk = it * 256 + tid;                                            \
      const int row = chunk >> 4, sc = (chunk & 15) ^ (row & 7);                   \
      gll16(kbase + (size_t)((kv)*64 + row) * 4608 + sc * 8,                       \
            &Ks[b][(it * 256 + wave * 64) * 8]);                                   \
    }                                                                              \
    _Pragma("unroll") for (int it = 0; it < 4; ++it) {                             \
      const int chunk = it * 256 + tid;                                            \
      const int row = chunk >> 3, sc = (chunk & 7) ^ (row & 7);                    \
      gll16(vbase + (size_t)row * 2048 + (kv)*64 + sc * 8,                         \
            &Vs[b][(it * 256 + wave * 64) * 8]);                                   \
    }                                                                              \
  }

  RESET();
  LOADQ(qtA);
  STAGE(0, 0);
  __syncthreads();
  int cur = 0;

  for (int s = 0; s < 33; ++s) {
    if (s < 32) {
      const int sn = s + 1;
      const int kvn = (sn <= qtA) ? sn : sn - qtA - 1;
      STAGE(kvn, cur ^ 1);
    }
    const int qt = (s <= qtA) ? qtA : qtB;
    const int kv = (s <= qtA) ? s : s - qtA - 1;
    const bool diag = (s == qtA) || (s == 32);

    f32x4 sf[4] = {};
    __builtin_amdgcn_s_setprio(1);
#pragma unroll
    for (int n = 0; n < 4; ++n) {
      const int krow = n * 16 + l15;
#pragma unroll
      for (int ds = 0; ds < 4; ++ds) {
        const int c = (ds * 4 + g) ^ (krow & 7);
        const bf16x8 kf = *(const bf16x8*)(&Ks[cur][krow * 128 + c * 8]);
        sf[n] = MFMA16(qf[ds], kf, sf[n]);
      }
    }
    __builtin_amdgcn_s_setprio(0);

    if (diag) {
#pragma unroll
      for (int r = 0; r < 4; ++r) {
        const int qr = qt * 64 + wave * 16 + g * 4 + r;
#pragma unroll
        for (int n = 0; n < 4; ++n)
          if (kv * 64 + n * 16 + l15 > qr) sf[n][r] = NINF;
      }
    }
    float pmax[4];
#pragma unroll
    for (int r = 0; r < 4; ++r)
      pmax[r] = fmaxf(fmaxf(sf[0][r], sf[1][r]), fmaxf(sf[2][r], sf[3][r]));
    const bool need = (pmax[0] > mrun[0] + 8.f) || (pmax[1] > mrun[1] + 8.f) ||
                      (pmax[2] > mrun[2] + 8.f) || (pmax[3] > mrun[3] + 8.f);
    if (__any(need)) {
#pragma unroll
      for (int r = 0; r < 4; ++r) {
        float mx = pmax[r];
        mx = fmaxf(mx, __shfl_xor(mx, 1));
        mx = fmaxf(mx, __shfl_xor(mx, 2));
        mx = fmaxf(mx, __shfl_xor(mx, 4));
        mx = fmaxf(mx, __shfl_xor(mx, 8));
        const float mnew = fmaxf(mrun[r], mx);
        const float alpha = exp2f(mrun[r] - mnew);
        mrun[r] = mnew;
        lrun[r] *= alpha;
#pragma unroll
        for (int nd = 0; nd < 8; ++nd) o[nd][r] *= alpha;
      }
    }
#pragma unroll
    for (int n = 0; n < 4; ++n) {
#pragma unroll
      for (int r = 0; r < 4; ++r) {
        const float p = exp2f(sf[n][r] - mrun[r]);
        lrun[r] += p;
        const int prow = g * 4 + r, key = n * 16 + l15;
        const int cp = (key >> 3) ^ (prow & 7);
        Ps[wave][prow * 64 + cp * 8 + (key & 7)] = f2bf(p);
      }
    }
    bf16x8 pf[2];
#pragma unroll
    for (int ksl = 0; ksl < 2; ++ksl) {
      const int c = (ksl * 4 + g) ^ (l15 & 7);
      pf[ksl] = *(const bf16x8*)(&Ps[wave][l15 * 64 + c * 8]);
    }
    __builtin_amdgcn_s_setprio(1);
#pragma unroll
    for (int nd = 0; nd < 8; ++nd) {
      const int vrow = nd * 16 + l15;
#pragma unroll
      for (int ksl = 0; ksl < 2; ++ksl) {
        const int c = (ksl * 4 + g) ^ (vrow & 7);
        const bf16x8 vf = *(const bf16x8*)(&Vs[cur][vrow * 64 + c * 8]);
        o[nd] = MFMA16(pf[ksl], vf, o[nd]);
      }
    }
    __builtin_amdgcn_s_setprio(0);

    if (diag) {
      float inv[4];
#pragma unroll
      for (int r = 0; r < 4; ++r) {
        float sum = lrun[r];
        sum += __shfl_xor(sum, 1);
        sum += __shfl_xor(sum, 2);
        sum += __shfl_xor(sum, 4);
        sum += __shfl_xor(sum, 8);
        inv[r] = 1.0f / sum;
      }
#pragma unroll
      for (int nd = 0; nd < 8; ++nd) {
#pragma unroll
        for (int r = 0; r < 4; ++r) {
          const int qr = qt * 64 + wave * 16 + g * 4 + r;
          outb[(size_t)qr * 3584 + head * 128 + nd * 16 + l15] = f2bf(o[nd][r] * inv[r]);
        }
      }
      if (s == qtA) {
        RESET();
        LOADQ(qtB);
      }
    }
    __syncthreads();
    cur ^= 1;
  }
#undef LOADQ
#undef RESET
#undef STAGE
}

extern "C" void kernel_launch(void* const* d_in, const int* in_sizes, int n_in,
                              void* d_out, int out_size, void* d_ws, size_t ws_size,
                              hipStream_t stream) {
  const float* h  = (const float*)d_in[0];
  const int* pos  = (const int*)d_in[1];
  const float* Wq = (const float*)d_in[2];
  const float* bq = (const float*)d_in[3];
  const float* Wk = (const float*)d_in[4];
  const float* bk = (const float*)d_in[5];
  const float* Wv = (const float*)d_in[6];
  const float* bv = (const float*)d_in[7];
  const float* Wo = (const float*)d_in[8];
  float* out = (float*)d_out;

  char* w = (char*)d_ws;
  short* hbf  = (short*)w; w += (size_t)2048 * 3584 * 2;
  short* Wall = (short*)w; w += (size_t)4608 * 3584 * 2;
  short* qkvp = (short*)w; w += (size_t)2048 * 4608 * 2;
  float* ctab = (float*)w; w += 2048 * 64 * 4;
  float* stab = (float*)w; w += 2048 * 64 * 4;
  short* vtb  = (short*)w; w += (size_t)4 * 128 * 2048 * 2;
  short* Pp   = (short*)w; w += (size_t)448 * 65536 * 2;  // 58.7 MB partials
  short* attnb = hbf;   // hbf dead after QKV GEMM
  short* Wob = Wall;    // Wall dead after QKV GEMM

  cvt4<<<2048, 256, 0, stream>>>(h, Wq, Wk, Wv, hbf, Wall);
  rope_table<<<2048, 64, 0, stream>>>(pos, ctab, stab);

  // QKV: per XCD one M-tile row x 18 N-tiles, 1008 units = 28 blocks x 36
  gemm_sk3<36><<<224, 512, 0, stream>>>(hbf, Wall, Pp, 3584);

  cvt_kernel<<<2048, 256, 0, stream>>>(Wo, Wob, (long long)3584 * 3584);
  rope_apply5<<<2048, 256, 0, stream>>>(Pp, bq, bk, ctab, stab, qkvp);
  v_transpose5<<<dim3(4, 32, 4), 256, 0, stream>>>(Pp, bv, vtb);

  attn_kernel<<<dim3(16, 28), 256, 0, stream>>>(qkvp, vtb, attnb);

  // O-proj: per XCD one M-tile row x 14 N-tiles, 784 units = 28 blocks x 28
  gemm_sk3<28><<<224, 512, 0, stream>>>(attnb, Wob, Pp, 3584);
  o_reduce3<<<3584, 256, 0, stream>>>(Pp, out);
}

// Round 12
// 421.712 us; speedup vs baseline: 1.2074x; 1.2074x over previous
//
#include <hip/hip_runtime.h>

typedef __attribute__((ext_vector_type(4))) float f32x4;
typedef __attribute__((ext_vector_type(8))) short bf16x8;
typedef __attribute__((ext_vector_type(4))) short bf16x4;

#define MFMA16(a, b, c) __builtin_amdgcn_mfma_f32_16x16x32_bf16((a), (b), (c), 0, 0, 0)
#define LOG2E 1.44269504088896340736f

static __device__ __forceinline__ float bf2f(short u) {
  unsigned x = ((unsigned)(unsigned short)u) << 16;
  return __builtin_bit_cast(float, x);
}
static __device__ __forceinline__ short f2bf(float f) {
  unsigned u = __builtin_bit_cast(unsigned, f);
  u += 0x7fffu + ((u >> 16) & 1u);
  return (short)(u >> 16);
}
// global -> LDS direct DMA, 16B per lane (guide §5); source pre-swizzled.
static __device__ __forceinline__ void gll16(const void* g, void* l) {
  __builtin_amdgcn_global_load_lds(
      (const __attribute__((address_space(1))) unsigned*)(unsigned long long)g,
      (__attribute__((address_space(3))) unsigned*)(unsigned)(unsigned long long)l,
      16, 0, 0);
}

// ------- merged f32 -> bf16 conversion: h, Wq, Wk, Wv in one launch --------
__global__ void __launch_bounds__(256) cvt4(const float* __restrict__ h,
                                            const float* __restrict__ wq,
                                            const float* __restrict__ wk,
                                            const float* __restrict__ wv,
                                            short* __restrict__ hbf,
                                            short* __restrict__ wall) {
  const long long C0 = 917504, C1 = 1605632, C2 = 229376;  // 8-elem chunks
  long long ch = (long long)blockIdx.x * 256 + threadIdx.x;
  const long long stride = (long long)gridDim.x * 256;
  const long long total = C0 + C1 + 2 * C2;
  for (; ch < total; ch += stride) {
    const float* s;
    short* d;
    long long off;
    if (ch < C0) { s = h; d = hbf; off = ch; }
    else if (ch < C0 + C1) { s = wq; d = wall; off = ch - C0; }
    else if (ch < C0 + C1 + C2) { s = wk; d = wall + (size_t)3584 * 3584; off = ch - C0 - C1; }
    else { s = wv; d = wall + (size_t)4096 * 3584; off = ch - C0 - C1 - C2; }
    const long long i = off * 8;
    f32x4 a = *(const f32x4*)(s + i);
    f32x4 b = *(const f32x4*)(s + i + 4);
    bf16x8 o;
    o[0] = f2bf(a[0]); o[1] = f2bf(a[1]); o[2] = f2bf(a[2]); o[3] = f2bf(a[3]);
    o[4] = f2bf(b[0]); o[5] = f2bf(b[1]); o[6] = f2bf(b[2]); o[7] = f2bf(b[3]);
    *(bf16x8*)(d + i) = o;
  }
}

__global__ void __launch_bounds__(256) cvt_kernel(const float* __restrict__ src,
                                                  short* __restrict__ dst,
                                                  long long n) {
  long long i = ((long long)blockIdx.x * 256 + threadIdx.x) * 8;
  const long long stride = (long long)gridDim.x * 256 * 8;
  for (; i < n; i += stride) {
    f32x4 a = *(const f32x4*)(src + i);
    f32x4 b = *(const f32x4*)(src + i + 4);
    bf16x8 o;
    o[0] = f2bf(a[0]); o[1] = f2bf(a[1]); o[2] = f2bf(a[2]); o[3] = f2bf(a[3]);
    o[4] = f2bf(b[0]); o[5] = f2bf(b[1]); o[6] = f2bf(b[2]); o[7] = f2bf(b[3]);
    *(bf16x8*)(dst + i) = o;
  }
}

// ---------------- RoPE cos/sin table: [2048][64] ----------------
__global__ void rope_table(const int* __restrict__ pos, float* __restrict__ ctab,
                           float* __restrict__ stab) {
  const int s = blockIdx.x;
  const int i = threadIdx.x;  // 0..63
  const float p = (float)pos[s];
  const float ang = p * exp2f(-(float)i * 0.3114307588956902f);
  ctab[s * 64 + i] = cosf(ang);
  stab[s * 64 + i] = sinf(ang);
}

// ---- stream-K partial gathers. 1x18 rects: xcd = tr (M-tile row), rt = tc.
// QKV: 36 units/block, tile = 56 units. Tile tc's contributors: j in
// [56tc/36, (56tc+55)/36]; seg = 0 iff tc is block j's FIRST tile.
// Slots row-major 256x256 bf16 at Pp[(xcd*28+j)*2+seg].
static __device__ __forceinline__ void qkv_gather(const short* __restrict__ Pp,
                                                  int tr, int tc, int s, int col0,
                                                  float* x, float* y) {
  const int j0 = (56 * tc) / 36, j1 = (56 * tc + 55) / 36;
  const size_t off = (size_t)(s & 255) * 256 + (col0 & 255);
#pragma unroll 1
  for (int j = j0; j <= j1; ++j) {
    const int seg = ((36 * j) / 56 == tc) ? 0 : 1;
    const short* p = Pp + ((size_t)((tr * 28 + j) * 2 + seg)) * 65536 + off;
    const bf16x8 lo = *(const bf16x8*)p;
    const bf16x8 hi = *(const bf16x8*)(p + 64);
#pragma unroll
    for (int q = 0; q < 8; ++q) { x[q] += bf2f(lo[q]); y[q] += bf2f(hi[q]); }
  }
}
static __device__ __forceinline__ void qkv_gather8(const short* __restrict__ Pp,
                                                   int tr, int tc, int s, int col0,
                                                   float* x) {
  const int j0 = (56 * tc) / 36, j1 = (56 * tc + 55) / 36;
  const size_t off = (size_t)(s & 255) * 256 + (col0 & 255);
#pragma unroll 1
  for (int j = j0; j <= j1; ++j) {
    const int seg = ((36 * j) / 56 == tc) ? 0 : 1;
    const short* p = Pp + ((size_t)((tr * 28 + j) * 2 + seg)) * 65536 + off;
    const bf16x8 lo = *(const bf16x8*)p;
#pragma unroll
    for (int q = 0; q < 8; ++q) x[q] += bf2f(lo[q]);
  }
}

// RoPE from QKV partials + bias -> bf16 qkvp (q,k regions). Q heads (h<28)
// pre-scaled by SCALE*LOG2E (exp2-domain scores).
__global__ void __launch_bounds__(256) rope_apply5(const short* __restrict__ Pp,
                                                   const float* __restrict__ bq,
                                                   const float* __restrict__ bk,
                                                   const float* __restrict__ ctab,
                                                   const float* __restrict__ stab,
                                                   short* __restrict__ qkvp) {
  const int idx = blockIdx.x * 256 + threadIdx.x;  // 2048*32*8
  const int c = idx & 7;
  const int h = (idx >> 3) & 31;
  const int s = idx >> 8;
  const int col0 = h * 128 + c * 8;  // < 4096; col0%256 <= 184, +64 stays in tile
  float x[8] = {}, y[8] = {};
  qkv_gather(Pp, s >> 8, col0 >> 8, s, col0, x, y);
  const float qs = (h < 28) ? (0.08838834764831845f * LOG2E) : 1.0f;
  const float* bl = (h < 28) ? (bq + col0) : (bk + col0 - 3584);
  const float* cp = ctab + s * 64 + c * 8;
  const float* sp = stab + s * 64 + c * 8;
  bf16x8 lo2, hi2;
#pragma unroll
  for (int j = 0; j < 8; ++j) {
    const float xv = x[j] + bl[j], yv = y[j] + bl[j + 64];
    const float cv = cp[j], sv = sp[j];
    lo2[j] = f2bf((xv * cv - yv * sv) * qs);
    hi2[j] = f2bf((yv * cv + xv * sv) * qs);
  }
  short* dst = qkvp + (size_t)s * 4608 + col0;
  *(bf16x8*)dst = lo2;
  *(bf16x8*)(dst + 64) = hi2;
}

// V region from partials + bias -> V^T bf16 [4][128][2048]
__global__ void __launch_bounds__(256) v_transpose5(const short* __restrict__ Pp,
                                                    const float* __restrict__ bv,
                                                    short* __restrict__ vtb) {
  __shared__ short t[64 * 48];
  const int dt = blockIdx.x, st = blockIdx.y, kv = blockIdx.z;
  const int tid = threadIdx.x;
  {
    const int r = tid >> 2, c8 = tid & 3;
    const int s = st * 64 + r;
    const int col0 = 4096 + kv * 128 + dt * 32 + c8 * 8;
    float x[8] = {};
    qkv_gather8(Pp, s >> 8, col0 >> 8, s, col0, x);
    const float* bp = bv + kv * 128 + dt * 32 + c8 * 8;
#pragma unroll
    for (int j = 0; j < 8; ++j) t[r * 48 + c8 * 8 + j] = f2bf(x[j] + bp[j]);
  }
  __syncthreads();
  {
    const int d = tid >> 3, c = tid & 7;
    bf16x8 v;
#pragma unroll
    for (int i = 0; i < 8; ++i) v[i] = t[(c * 8 + i) * 48 + d];
    *(bf16x8*)(vtb + ((size_t)kv * 128 + dt * 32 + d) * 2048 + st * 64 + c * 8) = v;
  }
}

// O-proj reduce: out = blocks 2tc, 2tc+1 (both seg 0), f32.
__global__ void __launch_bounds__(256) o_reduce3(const short* __restrict__ Pp,
                                                 float* __restrict__ out) {
  const int idx = blockIdx.x * 256 + threadIdx.x;  // 2048*448
  const int s = idx / 448;
  const int col0 = (idx % 448) * 8;
  const int tr = s >> 8, tc = col0 >> 8;  // tc 0..13
  const size_t off = (size_t)(s & 255) * 256 + (col0 & 255);
  const short* pA = Pp + ((size_t)((tr * 28 + 2 * tc) * 2)) * 65536 + off;
  const short* pB = Pp + ((size_t)((tr * 28 + 2 * tc + 1) * 2)) * 65536 + off;
  const bf16x8 a = *(const bf16x8*)pA;
  const bf16x8 b = *(const bf16x8*)pB;
  f32x4 o1, o2;
#pragma unroll
  for (int q = 0; q < 4; ++q) {
    o1[q] = bf2f(a[q]) + bf2f(b[q]);
    o2[q] = bf2f(a[q + 4]) + bf2f(b[q + 4]);
  }
  float* dst = out + (size_t)s * 3584 + col0;
  *(f32x4*)dst = o1;
  *(f32x4*)(dst + 4) = o2;
}

// ---- stream-K 8-phase bf16 GEMM, 1x18 XCD rect, LDS-repack epilogue -------
// A[2048,K]*B[N,K]^T. 224 blocks: xcd=bid&7 owns M-tile-row xcd -> the
// block's A panel (256 rows x K, 1.8 MB) is FIXED and L2-resident; B streams
// via L3. In-rect units u=(tc,kt)=(u/56,u%56); block jj=bid>>3 owns
// [UNITS*jj, UNITS*jj+UNITS). Phase/sync/vmcnt engine identical to r7.
// Epilogue: acc -> Es (32KB LDS, 4 row-groups of 64) -> FULL-512B-row global
// stores (lane L writes cols 4L..4L+3) -> row-major slots, no partial cache
// lines (r9/r11's 4x write-amplification + write-allocate eliminated).
// Mid-epilogue barriers are block-uniform. Stores inflate vmcnt -> later
// counted waits only get stronger.
template <int UNITS>
__global__ void __launch_bounds__(512, 2)
gemm_sk4(const short* __restrict__ A, const short* __restrict__ B,
         short* __restrict__ Pp, int K) {
  __shared__ short As[2][256 * 64];
  __shared__ short Bs[2][256 * 64];
  __shared__ short Es[64 * 256];  // total LDS = 163840 B = 160 KiB exactly
  const int bid = (int)blockIdx.x;
  const int xcd = bid & 7, jj = bid >> 3;
  const int u0 = jj * UNITS;
  const int T0 = u0 / 56;
  const int Tend = (u0 + UNITS - 1) / 56;
  const int kb1 = 56 * (T0 + 1);
  const int tm = xcd << 8;
  const int tid = (int)threadIdx.x;
  const int wave = tid >> 6, lane = tid & 63;
  const int l15 = lane & 15, g = lane >> 4;
  const int wm = wave >> 2, wn = wave & 3;

  f32x4 acc[2][4][2][2] = {};  // [rh][mq][ch][nq]
  bf16x8 af[4][2], b0[2][2], b1[2][2];

#define STG_A(b, uu, h)                                                         \
  { const int kt_ = (uu) % 56;                                                  \
    _Pragma("unroll") for (int jq = 0; jq < 2; ++jq) {                          \
      const int lr = (h) * 128 + jq * 64 + (tid >> 3);                          \
      const int wmm = (lr >> 6) & 1;                                            \
      const int rr = lr & 63;                                                   \
      const int grow = wmm * 128 + (h) * 64 + rr;                               \
      const int sc = (tid & 7) ^ (rr & 7);                                      \
      gll16(A + (size_t)(tm + grow) * K + (size_t)kt_ * 64 + sc * 8,            \
            &As[b][((h) * 128 + jq * 64 + wave * 8) * 64]);                     \
    } }
#define STG_B(b, uu, h)                                                         \
  { const int tc_ = (uu) / 56, kt_ = (uu)-tc_ * 56;                             \
    const int tn_ = tc_ << 8;                                                   \
    _Pragma("unroll") for (int jq = 0; jq < 2; ++jq) {                          \
      const int lr = (h) * 128 + jq * 64 + (tid >> 3);                          \
      const int wnn = (lr >> 5) & 3;                                            \
      const int rr = lr & 31;                                                   \
      const int gcol = wnn * 64 + (h) * 32 + rr;                                \
      const int sc = (tid & 7) ^ (rr & 7);                                      \
      gll16(B + (size_t)(tn_ + gcol) * K + (size_t)kt_ * 64 + sc * 8,           \
            &Bs[b][((h) * 128 + jq * 64 + wave * 8) * 64]);                     \
    } }
#define LDA(buf, rh)                                                            \
  { _Pragma("unroll") for (int mq = 0; mq < 4; ++mq)                            \
      _Pragma("unroll") for (int ks = 0; ks < 2; ++ks) {                        \
        const int lr = (rh) * 128 + wm * 64 + mq * 16 + l15;                    \
        af[mq][ks] =                                                            \
            *(const bf16x8*)(&As[buf][lr * 64 + (((ks * 4 + g) ^ (lr & 7)) * 8)]); \
      } }
#define LDB(buf, ch, ARR)                                                       \
  { _Pragma("unroll") for (int nq = 0; nq < 2; ++nq)                            \
      _Pragma("unroll") for (int ks = 0; ks < 2; ++ks) {                        \
        const int lr = (ch) * 128 + wn * 32 + nq * 16 + l15;                    \
        ARR[nq][ks] =                                                           \
            *(const bf16x8*)(&Bs[buf][lr * 64 + (((ks * 4 + g) ^ (lr & 7)) * 8)]); \
      } }
#define VMW() { asm volatile("s_waitcnt vmcnt(4)" ::: "memory"); }
#define PH(RH, CH, BARR, TAILBLK)                                               \
  {                                                                             \
    __builtin_amdgcn_s_barrier();                                               \
    asm volatile("s_waitcnt lgkmcnt(0)" ::: "memory");                          \
    __builtin_amdgcn_sched_barrier(0);                                          \
    __builtin_amdgcn_s_setprio(1);                                              \
    _Pragma("unroll") for (int mq = 0; mq < 4; ++mq)                            \
      _Pragma("unroll") for (int nq = 0; nq < 2; ++nq) {                        \
        acc[RH][mq][CH][nq] = MFMA16(af[mq][0], BARR[nq][0], acc[RH][mq][CH][nq]); \
        acc[RH][mq][CH][nq] = MFMA16(af[mq][1], BARR[nq][1], acc[RH][mq][CH][nq]); \
      }                                                                         \
    __builtin_amdgcn_s_setprio(0);                                              \
    TAILBLK;                                                                    \
    __builtin_amdgcn_sched_barrier(0);                                          \
  }
// Epilogue via LDS repack: 4 row-groups of 64; scatter (only waves with
// wm==rg>>1 hold this group's rows) -> barrier -> full-row coalesced stores
// (wave w stores rows w*8..w*8+7; lane L -> cols 4L..4L+3, 512B/instr).
#define PEPI(seg)                                                               \
  { short* pb = Pp + ((size_t)(((xcd * 28 + jj) << 1) + (seg))) * 65536;        \
    _Pragma("unroll") for (int rg = 0; rg < 4; ++rg) {                          \
      if (wm == (rg >> 1)) {                                                    \
        _Pragma("unroll") for (int mq = 0; mq < 4; ++mq)                        \
        _Pragma("unroll") for (int ch = 0; ch < 2; ++ch)                        \
        _Pragma("unroll") for (int nq = 0; nq < 2; ++nq)                        \
        _Pragma("unroll") for (int r = 0; r < 4; ++r)                           \
          Es[(mq * 16 + g * 4 + r) * 256 + wn * 64 + ch * 32 + nq * 16 + l15] = \
              f2bf(acc[rg & 1][mq][ch][nq][r]);                                 \
      }                                                                         \
      asm volatile("s_waitcnt lgkmcnt(0)" ::: "memory");                        \
      __builtin_amdgcn_s_barrier();                                             \
      _Pragma("unroll") for (int rr = 0; rr < 8; ++rr) {                        \
        const int rl = wave * 8 + rr;                                           \
        *(bf16x4*)(pb + (size_t)(rg * 64 + rl) * 256 + lane * 4) =              \
            *(const bf16x4*)(&Es[rl * 256 + lane * 4]);                         \
      }                                                                         \
      asm volatile("s_waitcnt lgkmcnt(0)" ::: "memory");                        \
      __builtin_amdgcn_s_barrier();                                             \
    } }
#define RSTACC()                                                                \
  { _Pragma("unroll") for (int rh = 0; rh < 2; ++rh)                            \
    _Pragma("unroll") for (int mq = 0; mq < 4; ++mq)                            \
    _Pragma("unroll") for (int ch = 0; ch < 2; ++ch)                            \
    _Pragma("unroll") for (int nq = 0; nq < 2; ++nq)                            \
      acc[rh][mq][ch][nq] = f32x4{0.f, 0.f, 0.f, 0.f}; }

  // prologue: stage units u0 (buf0), u0+1 (buf1); drain u0; read P1 frags.
  STG_A(0, u0, 0); STG_A(0, u0, 1); STG_B(0, u0, 0); STG_B(0, u0, 1);
  STG_A(1, u0 + 1, 0); STG_A(1, u0 + 1, 1); STG_B(1, u0 + 1, 0); STG_B(1, u0 + 1, 1);
  asm volatile("s_waitcnt vmcnt(8)" ::: "memory");
  __builtin_amdgcn_s_barrier();
  LDA(0, 0); LDB(0, 0, b0);

#pragma unroll 1
  for (int i = 0; i < UNITS / 2; ++i) {
    const int uu2 = u0 + 2 * i + 2, uu3 = uu2 + 1;
    const bool more = (i < UNITS / 2 - 1);
    PH(0, 0, b0, { LDB(0, 1, b1); });
    PH(0, 1, b1, { if (more) STG_A(0, uu2, 0); LDA(0, 1); });
    PH(1, 1, b1, { if (more) { STG_B(0, uu2, 1); VMW(); }
                   else { asm volatile("s_waitcnt vmcnt(0)" ::: "memory"); } });
    PH(1, 0, b0, { if (more) { STG_A(0, uu2, 1); STG_B(0, uu2, 0); }
                   LDA(1, 0); LDB(1, 0, b0); });
    PH(0, 0, b0, { LDB(1, 1, b1); });
    PH(0, 1, b1, { if (more) STG_A(1, uu3, 0); LDA(1, 1); });
    PH(1, 1, b1, { if (more) { STG_B(1, uu3, 1); VMW(); } });
    PH(1, 0, b0, { if (more) { STG_A(1, uu3, 1); STG_B(1, uu3, 0);
                               LDA(0, 0); LDB(0, 0, b0); } });
    // tile boundary (even parity -> only possible here); never on last iter.
    if (Tend > T0 && (u0 + 2 * i + 2 == kb1)) { PEPI(0); RSTACC(); }
  }
  PEPI((Tend > T0) ? 1 : 0);
#undef STG_A
#undef STG_B
#undef LDA
#undef LDB
#undef VMW
#undef PH
#undef PEPI
#undef RSTACC
}

// ---------------- flash attention, 2-phase pipelined, paired q-tiles --------
__global__ void __launch_bounds__(256) attn_kernel(const short* __restrict__ qkv,
                                                   const short* __restrict__ vtb,
                                                   short* __restrict__ outb) {
  const int lid = (int)blockIdx.x + ((int)blockIdx.y << 4);
  const int kvh = (lid & 7) >> 1;
  const int u = ((lid >> 3) << 1) + (lid & 1);  // 0..111 within kv group
  const int head = kvh * 7 + (u >> 4);
  const int qtA = u & 15, qtB = 31 - qtA;

  const int tid = threadIdx.x;
  const int lane = tid & 63, wave = tid >> 6;
  const int l15 = lane & 15, g = lane >> 4;

  __shared__ short Ks[2][64 * 128];
  __shared__ short Vs[2][128 * 64];
  __shared__ short Ps[4][16 * 64];

  const short* kbase = qkv + 3584 + kvh * 128;
  const short* vbase = vtb + (size_t)kvh * 128 * 2048;
  const float NINF = -__builtin_inff();

  bf16x8 qf[4];
  f32x4 o[8];
  float mrun[4], lrun[4];

#define LOADQ(qt)                                                                  \
  {                                                                                \
    const short* qptr =                                                            \
        qkv + (size_t)((qt)*64 + wave * 16 + l15) * 4608 + head * 128 + g * 8;     \
    _Pragma("unroll") for (int ds = 0; ds < 4; ++ds) qf[ds] =                      \
        *(const bf16x8*)(qptr + ds * 32);                                          \
  }
#define RESET()                                                                    \
  {                                                                                \
    _Pragma("unroll") for (int nd = 0; nd < 8; ++nd) o[nd] = f32x4{0.f,0.f,0.f,0.f}; \
    _Pragma("unroll") for (int r = 0; r < 4; ++r) { mrun[r] = NINF; lrun[r] = 0.f; } \
  }
#define STAGE(kv, b)                                                               \
  {                                                                                \
    _Pragma("unroll") for (int it = 0; it < 4; ++it) {                             \
      const int chunk = it * 256 + tid;                                            \
      const int row = chunk >> 4, sc = (chunk & 15) ^ (row & 7);                   \
      gll16(kbase + (size_t)((kv)*64 + row) * 4608 + sc * 8,                       \
            &Ks[b][(it * 256 + wave * 64) * 8]);                                   \
    }                                                                              \
    _Pragma("unroll") for (int it = 0; it < 4; ++it) {                             \
      const int chunk = it * 256 + tid;                                            \
      const int row = chunk >> 3, sc = (chunk & 7) ^ (row & 7);                    \
      gll16(vbase + (size_t)row * 2048 + (kv)*64 + sc * 8,                         \
            &Vs[b][(it * 256 + wave * 64) * 8]);                                   \
    }                                                                              \
  }

  RESET();
  LOADQ(qtA);
  STAGE(0, 0);
  __syncthreads();
  int cur = 0;

  for (int s = 0; s < 33; ++s) {
    if (s < 32) {
      const int sn = s + 1;
      const int kvn = (sn <= qtA) ? sn : sn - qtA - 1;
      STAGE(kvn, cur ^ 1);
    }
    const int qt = (s <= qtA) ? qtA : qtB;
    const int kv = (s <= qtA) ? s : s - qtA - 1;
    const bool diag = (s == qtA) || (s == 32);

    f32x4 sf[4] = {};
    __builtin_amdgcn_s_setprio(1);
#pragma unroll
    for (int n = 0; n < 4; ++n) {
      const int krow = n * 16 + l15;
#pragma unroll
      for (int ds = 0; ds < 4; ++ds) {
        const int c = (ds * 4 + g) ^ (krow & 7);
        const bf16x8 kf = *(const bf16x8*)(&Ks[cur][krow * 128 + c * 8]);
        sf[n] = MFMA16(qf[ds], kf, sf[n]);
      }
    }
    __builtin_amdgcn_s_setprio(0);

    if (diag) {
#pragma unroll
      for (int r = 0; r < 4; ++r) {
        const int qr = qt * 64 + wave * 16 + g * 4 + r;
#pragma unroll
        for (int n = 0; n < 4; ++n)
          if (kv * 64 + n * 16 + l15 > qr) sf[n][r] = NINF;
      }
    }
    float pmax[4];
#pragma unroll
    for (int r = 0; r < 4; ++r)
      pmax[r] = fmaxf(fmaxf(sf[0][r], sf[1][r]), fmaxf(sf[2][r], sf[3][r]));
    const bool need = (pmax[0] > mrun[0] + 8.f) || (pmax[1] > mrun[1] + 8.f) ||
                      (pmax[2] > mrun[2] + 8.f) || (pmax[3] > mrun[3] + 8.f);
    if (__any(need)) {
#pragma unroll
      for (int r = 0; r < 4; ++r) {
        float mx = pmax[r];
        mx = fmaxf(mx, __shfl_xor(mx, 1));
        mx = fmaxf(mx, __shfl_xor(mx, 2));
        mx = fmaxf(mx, __shfl_xor(mx, 4));
        mx = fmaxf(mx, __shfl_xor(mx, 8));
        const float mnew = fmaxf(mrun[r], mx);
        const float alpha = exp2f(mrun[r] - mnew);
        mrun[r] = mnew;
        lrun[r] *= alpha;
#pragma unroll
        for (int nd = 0; nd < 8; ++nd) o[nd][r] *= alpha;
      }
    }
#pragma unroll
    for (int n = 0; n < 4; ++n) {
#pragma unroll
      for (int r = 0; r < 4; ++r) {
        const float p = exp2f(sf[n][r] - mrun[r]);
        lrun[r] += p;
        const int prow = g * 4 + r, key = n * 16 + l15;
        const int cp = (key >> 3) ^ (prow & 7);
        Ps[wave][prow * 64 + cp * 8 + (key & 7)] = f2bf(p);
      }
    }
    bf16x8 pf[2];
#pragma unroll
    for (int ksl = 0; ksl < 2; ++ksl) {
      const int c = (ksl * 4 + g) ^ (l15 & 7);
      pf[ksl] = *(const bf16x8*)(&Ps[wave][l15 * 64 + c * 8]);
    }
    __builtin_amdgcn_s_setprio(1);
#pragma unroll
    for (int nd = 0; nd < 8; ++nd) {
      const int vrow = nd * 16 + l15;
#pragma unroll
      for (int ksl = 0; ksl < 2; ++ksl) {
        const int c = (ksl * 4 + g) ^ (vrow & 7);
        const bf16x8 vf = *(const bf16x8*)(&Vs[cur][vrow * 64 + c * 8]);
        o[nd] = MFMA16(pf[ksl], vf, o[nd]);
      }
    }
    __builtin_amdgcn_s_setprio(0);

    if (diag) {
      float inv[4];
#pragma unroll
      for (int r = 0; r < 4; ++r) {
        float sum = lrun[r];
        sum += __shfl_xor(sum, 1);
        sum += __shfl_xor(sum, 2);
        sum += __shfl_xor(sum, 4);
        sum += __shfl_xor(sum, 8);
        inv[r] = 1.0f / sum;
      }
#pragma unroll
      for (int nd = 0; nd < 8; ++nd) {
#pragma unroll
        for (int r = 0; r < 4; ++r) {
          const int qr = qt * 64 + wave * 16 + g * 4 + r;
          outb[(size_t)qr * 3584 + head * 128 + nd * 16 + l15] = f2bf(o[nd][r] * inv[r]);
        }
      }
      if (s == qtA) {
        RESET();
        LOADQ(qtB);
      }
    }
    __syncthreads();
    cur ^= 1;
  }
#undef LOADQ
#undef RESET
#undef STAGE
}

extern "C" void kernel_launch(void* const* d_in, const int* in_sizes, int n_in,
                              void* d_out, int out_size, void* d_ws, size_t ws_size,
                              hipStream_t stream) {
  const float* h  = (const float*)d_in[0];
  const int* pos  = (const int*)d_in[1];
  const float* Wq = (const float*)d_in[2];
  const float* bq = (const float*)d_in[3];
  const float* Wk = (const float*)d_in[4];
  const float* bk = (const float*)d_in[5];
  const float* Wv = (const float*)d_in[6];
  const float* bv = (const float*)d_in[7];
  const float* Wo = (const float*)d_in[8];
  float* out = (float*)d_out;

  char* w = (char*)d_ws;
  short* hbf  = (short*)w; w += (size_t)2048 * 3584 * 2;
  short* Wall = (short*)w; w += (size_t)4608 * 3584 * 2;
  short* qkvp = (short*)w; w += (size_t)2048 * 4608 * 2;
  float* ctab = (float*)w; w += 2048 * 64 * 4;
  float* stab = (float*)w; w += 2048 * 64 * 4;
  short* vtb  = (short*)w; w += (size_t)4 * 128 * 2048 * 2;
  short* Pp   = (short*)w; w += (size_t)448 * 65536 * 2;  // 58.7 MB partials
  short* attnb = hbf;   // hbf dead after QKV GEMM
  short* Wob = Wall;    // Wall dead after QKV GEMM

  cvt4<<<2048, 256, 0, stream>>>(h, Wq, Wk, Wv, hbf, Wall);
  rope_table<<<2048, 64, 0, stream>>>(pos, ctab, stab);

  // QKV: per XCD one M-tile row x 18 N-tiles, 1008 units = 28 blocks x 36
  gemm_sk4<36><<<224, 512, 0, stream>>>(hbf, Wall, Pp, 3584);

  cvt_kernel<<<2048, 256, 0, stream>>>(Wo, Wob, (long long)3584 * 3584);
  rope_apply5<<<2048, 256, 0, stream>>>(Pp, bq, bk, ctab, stab, qkvp);
  v_transpose5<<<dim3(4, 32, 4), 256, 0, stream>>>(Pp, bv, vtb);

  attn_kernel<<<dim3(16, 28), 256, 0, stream>>>(qkvp, vtb, attnb);

  // O-proj: per XCD one M-tile row x 14 N-tiles, 784 units = 28 blocks x 28
  gemm_sk4<28><<<224, 512, 0, stream>>>(attnb, Wob, Pp, 3584);
  o_reduce3<<<3584, 256, 0, stream>>>(Pp, out);
}

// Round 13
// 236.134 us; speedup vs baseline: 2.1563x; 1.7859x over previous
//
#include <hip/hip_runtime.h>

typedef __attribute__((ext_vector_type(4))) float f32x4;
typedef __attribute__((ext_vector_type(8))) short bf16x8;

#define MFMA16(a, b, c) __builtin_amdgcn_mfma_f32_16x16x32_bf16((a), (b), (c), 0, 0, 0)
#define LOG2E 1.44269504088896340736f

static __device__ __forceinline__ float bf2f(short u) {
  unsigned x = ((unsigned)(unsigned short)u) << 16;
  return __builtin_bit_cast(float, x);
}
static __device__ __forceinline__ short f2bf(float f) {
  unsigned u = __builtin_bit_cast(unsigned, f);
  u += 0x7fffu + ((u >> 16) & 1u);
  return (short)(u >> 16);
}
// global -> LDS direct DMA, 16B per lane (guide §5); source pre-swizzled.
static __device__ __forceinline__ void gll16(const void* g, void* l) {
  __builtin_amdgcn_global_load_lds(
      (const __attribute__((address_space(1))) unsigned*)(unsigned long long)g,
      (__attribute__((address_space(3))) unsigned*)(unsigned)(unsigned long long)l,
      16, 0, 0);
}

// ------- merged f32 -> bf16 conversion: h, Wq, Wk, Wv in one launch --------
__global__ void __launch_bounds__(256) cvt4(const float* __restrict__ h,
                                            const float* __restrict__ wq,
                                            const float* __restrict__ wk,
                                            const float* __restrict__ wv,
                                            short* __restrict__ hbf,
                                            short* __restrict__ wall) {
  const long long C0 = 917504, C1 = 1605632, C2 = 229376;  // 8-elem chunks
  long long ch = (long long)blockIdx.x * 256 + threadIdx.x;
  const long long stride = (long long)gridDim.x * 256;
  const long long total = C0 + C1 + 2 * C2;
  for (; ch < total; ch += stride) {
    const float* s;
    short* d;
    long long off;
    if (ch < C0) { s = h; d = hbf; off = ch; }
    else if (ch < C0 + C1) { s = wq; d = wall; off = ch - C0; }
    else if (ch < C0 + C1 + C2) { s = wk; d = wall + (size_t)3584 * 3584; off = ch - C0 - C1; }
    else { s = wv; d = wall + (size_t)4096 * 3584; off = ch - C0 - C1 - C2; }
    const long long i = off * 8;
    f32x4 a = *(const f32x4*)(s + i);
    f32x4 b = *(const f32x4*)(s + i + 4);
    bf16x8 o;
    o[0] = f2bf(a[0]); o[1] = f2bf(a[1]); o[2] = f2bf(a[2]); o[3] = f2bf(a[3]);
    o[4] = f2bf(b[0]); o[5] = f2bf(b[1]); o[6] = f2bf(b[2]); o[7] = f2bf(b[3]);
    *(bf16x8*)(d + i) = o;
  }
}

__global__ void bias_concat(const float* __restrict__ bq, const float* __restrict__ bk,
                            const float* __restrict__ bv, float* __restrict__ ball) {
  const int i = blockIdx.x * 256 + threadIdx.x;
  if (i < 3584) ball[i] = bq[i];
  else if (i < 4096) ball[i] = bk[i - 3584];
  else if (i < 4608) ball[i] = bv[i - 4096];
}

// ---------------- RoPE cos/sin table: [2048][64] ----------------
__global__ void rope_table(const int* __restrict__ pos, float* __restrict__ ctab,
                           float* __restrict__ stab) {
  const int s = blockIdx.x;
  const int i = threadIdx.x;  // 0..63
  const float p = (float)pos[s];
  const float ang = p * exp2f(-(float)i * 0.3114307588956902f);
  ctab[s * 64 + i] = cosf(ang);
  stab[s * 64 + i] = sinf(ang);
}

// In-place RoPE on q/k regions of qkv[2048][4608]. Q heads (h<28) are
// pre-scaled by SCALE*LOG2E so attention scores come out in exp2-domain.
__global__ void __launch_bounds__(256) rope_apply(short* __restrict__ qkv,
                                                  const float* __restrict__ ctab,
                                                  const float* __restrict__ stab) {
  const int idx = blockIdx.x * 256 + threadIdx.x;  // 2048*32*8
  const int c = idx & 7;
  const int h = (idx >> 3) & 31;
  const int s = idx >> 8;
  const float qs = (h < 28) ? (0.08838834764831845f * LOG2E) : 1.0f;
  short* base = qkv + (size_t)s * 4608 + h * 128 + c * 8;
  bf16x8 lo = *(bf16x8*)base;
  bf16x8 hi = *(bf16x8*)(base + 64);
  const float* cp = ctab + s * 64 + c * 8;
  const float* sp = stab + s * 64 + c * 8;
  bf16x8 lo2, hi2;
#pragma unroll
  for (int j = 0; j < 8; ++j) {
    const float x = bf2f(lo[j]), y = bf2f(hi[j]);
    const float cv = cp[j], sv = sp[j];
    lo2[j] = f2bf((x * cv - y * sv) * qs);
    hi2[j] = f2bf((y * cv + x * sv) * qs);
  }
  *(bf16x8*)base = lo2;
  *(bf16x8*)(base + 64) = hi2;
}

// V region of qkv -> V^T [4][128][2048]
__global__ void __launch_bounds__(256) v_transpose(const short* __restrict__ qkv,
                                                   short* __restrict__ vtb) {
  __shared__ short t[64 * 48];
  const int dt = blockIdx.x, st = blockIdx.y, kv = blockIdx.z;
  const int tid = threadIdx.x;
  {
    const int r = tid >> 2, c8 = tid & 3;
    const bf16x8 v = *(const bf16x8*)(qkv + (size_t)(st * 64 + r) * 4608 + 4096 +
                                      kv * 128 + dt * 32 + c8 * 8);
    *(bf16x8*)(t + r * 48 + c8 * 8) = v;
  }
  __syncthreads();
  {
    const int d = tid >> 3, c = tid & 7;
    bf16x8 v;
#pragma unroll
    for (int i = 0; i < 8; ++i) v[i] = t[(c * 8 + i) * 48 + d];
    *(bf16x8*)(vtb + ((size_t)kv * 128 + dt * 32 + d) * 2048 + st * 64 + c * 8) = v;
  }
}

// --- 8-phase bf16 GEMM, read-ahead tails (r7-proven, 87 us) -----------------
// C[M=2048,N] = A[M,K]*B[N,K]^T (+bias). BMx256 tile, 8 waves (2M x 4N),
// BK=64, 2 K-tiles/iter double-buffered. Phase = {bar; lgkmcnt(0);
// sched_barrier; 16 MFMA setprio'd; tail: STG -> [VMW] -> READ next frags}.
// Lockstep per-tile blocks -> same-instant L2 sharing (FETCH 79 MB; stream-K
// variants all regress to 240+ MB). 2D XCD chunking: xcd=bid&7 owns an
// MCHxNCH tile rect. HETERO: blocks with idx >= MCH*NCH convert Wo instead
// (fills the otherwise-idle CUs with the independent 77 MB cvt).
template <int BM, int NT, int MCH, int NCH, bool BIAS, bool OUTBF, bool HETERO>
__global__ void __launch_bounds__(512, 2)
gemm10(const short* __restrict__ A, const short* __restrict__ B,
       const float* __restrict__ bias, void* __restrict__ outp, int N, int K,
       const float* __restrict__ xsrc, short* __restrict__ xdst) {
  constexpr int MQ2 = BM / 64;     // m-frags per rh-half (256->4, 128->2)
  constexpr int ACH = BM / 128;    // gll16 calls per A half-tile
  __shared__ short As[2][BM * 64];
  __shared__ short Bs[2][256 * 64];
  const int bid = (int)blockIdx.x;
  const int tid = (int)threadIdx.x;
  if (HETERO && (bid >> 3) >= MCH * NCH) {
    // cvt role: blocks 144..255 convert Wo (f32 -> bf16), grid-stride.
    const int cb = bid - 8 * MCH * NCH;  // 0..111
    long long i = ((long long)cb * 512 + tid) * 8;
    const long long stride = (long long)112 * 512 * 8;
    const long long n = (long long)3584 * 3584;
    for (; i < n; i += stride) {
      f32x4 a = *(const f32x4*)(xsrc + i);
      f32x4 b = *(const f32x4*)(xsrc + i + 4);
      bf16x8 o;
      o[0] = f2bf(a[0]); o[1] = f2bf(a[1]); o[2] = f2bf(a[2]); o[3] = f2bf(a[3]);
      o[4] = f2bf(b[0]); o[5] = f2bf(b[1]); o[6] = f2bf(b[2]); o[7] = f2bf(b[3]);
      *(bf16x8*)(xdst + i) = o;
    }
    return;
  }
  const int xcd = bid & 7, idx = bid >> 3;
  const int rowg = xcd / (NT / NCH), colg = xcd % (NT / NCH);
  const int tm = (rowg * MCH + idx % MCH) * BM;
  const int tn = (colg * NCH + idx / MCH) * 256;
  const int wave = tid >> 6, lane = tid & 63;
  const int l15 = lane & 15, g = lane >> 4;
  const int wm = wave >> 2, wn = wave & 3;

  f32x4 acc[2][MQ2][2][2] = {};  // [rh][mq][ch][nq]
  bf16x8 af[MQ2][2], b0[2][2], b1[2][2];

#define STG_A(b, kt, h)                                                         \
  { _Pragma("unroll") for (int j = 0; j < ACH; ++j) {                           \
      const int lr = (h) * (BM / 2) + j * 64 + (tid >> 3);                      \
      const int wmm = (lr / (BM / 4)) & 1;                                      \
      const int rr = lr & (BM / 4 - 1);                                         \
      const int grow = wmm * (BM / 2) + (h) * (BM / 4) + rr;                    \
      const int sc = (tid & 7) ^ (rr & 7);                                      \
      gll16(A + (size_t)(tm + grow) * K + (size_t)(kt) * 64 + sc * 8,           \
            &As[b][((h) * (BM / 2) + j * 64 + wave * 8) * 64]);                 \
    } }
#define STG_B(b, kt, h)                                                         \
  { _Pragma("unroll") for (int j = 0; j < 2; ++j) {                             \
      const int lr = (h) * 128 + j * 64 + (tid >> 3);                           \
      const int wnn = (lr >> 5) & 3;                                            \
      const int rr = lr & 31;                                                   \
      const int gcol = wnn * 64 + (h) * 32 + rr;                                \
      const int sc = (tid & 7) ^ (rr & 7);                                      \
      gll16(B + (size_t)(tn + gcol) * K + (size_t)(kt) * 64 + sc * 8,           \
            &Bs[b][((h) * 128 + j * 64 + wave * 8) * 64]);                      \
    } }
#define LDA(buf, rh)                                                            \
  { _Pragma("unroll") for (int mq = 0; mq < MQ2; ++mq)                          \
      _Pragma("unroll") for (int ks = 0; ks < 2; ++ks) {                        \
        const int lr = (rh) * (BM / 2) + wm * (BM / 4) + mq * 16 + l15;         \
        af[mq][ks] =                                                            \
            *(const bf16x8*)(&As[buf][lr * 64 + (((ks * 4 + g) ^ (lr & 7)) * 8)]); \
      } }
#define LDB(buf, ch, ARR)                                                       \
  { _Pragma("unroll") for (int nq = 0; nq < 2; ++nq)                            \
      _Pragma("unroll") for (int ks = 0; ks < 2; ++ks) {                        \
        const int lr = (ch) * 128 + wn * 32 + nq * 16 + l15;                    \
        ARR[nq][ks] =                                                           \
            *(const bf16x8*)(&Bs[buf][lr * 64 + (((ks * 4 + g) ^ (lr & 7)) * 8)]); \
      } }
#define VMW()                                                                   \
  { if constexpr (ACH == 2) { asm volatile("s_waitcnt vmcnt(4)" ::: "memory"); }\
    else { asm volatile("s_waitcnt vmcnt(3)" ::: "memory"); } }
#define PH(RH, CH, BARR, TAILBLK)                                               \
  {                                                                             \
    __builtin_amdgcn_s_barrier();                                               \
    asm volatile("s_waitcnt lgkmcnt(0)" ::: "memory");                          \
    __builtin_amdgcn_sched_barrier(0);                                          \
    __builtin_amdgcn_s_setprio(1);                                              \
    _Pragma("unroll") for (int mq = 0; mq < MQ2; ++mq)                          \
      _Pragma("unroll") for (int nq = 0; nq < 2; ++nq) {                        \
        acc[RH][mq][CH][nq] = MFMA16(af[mq][0], BARR[nq][0], acc[RH][mq][CH][nq]); \
        acc[RH][mq][CH][nq] = MFMA16(af[mq][1], BARR[nq][1], acc[RH][mq][CH][nq]); \
      }                                                                         \
    __builtin_amdgcn_s_setprio(0);                                              \
    TAILBLK;                                                                    \
    __builtin_amdgcn_sched_barrier(0);                                          \
  }

  // prologue: stage t0+t1; wait t0 landed; barrier; read P1's frags.
  STG_A(0, 0, 0); STG_A(0, 0, 1); STG_B(0, 0, 0); STG_B(0, 0, 1);
  STG_A(1, 1, 0); STG_A(1, 1, 1); STG_B(1, 1, 0); STG_B(1, 1, 1);
  if constexpr (ACH == 2) { asm volatile("s_waitcnt vmcnt(8)" ::: "memory"); }
  else                    { asm volatile("s_waitcnt vmcnt(6)" ::: "memory"); }
  __builtin_amdgcn_s_barrier();
  LDA(0, 0); LDB(0, 0, b0);

  const int L = K >> 7;  // 28 iterations, 2 K-tiles each
  for (int i = 0; i < L; ++i) {
    const int t2 = 2 * i + 2, t3 = 2 * i + 3;
    const bool more = (i < L - 1);
    PH(0, 0, b0, { LDB(0, 1, b1); });
    PH(0, 1, b1, { if (more) STG_A(0, t2, 0); LDA(0, 1); });
    PH(1, 1, b1, { if (more) { STG_B(0, t2, 1); VMW(); }
                   else { asm volatile("s_waitcnt vmcnt(0)" ::: "memory"); } });
    PH(1, 0, b0, { if (more) { STG_A(0, t2, 1); STG_B(0, t2, 0); }
                   LDA(1, 0); LDB(1, 0, b0); });
    PH(0, 0, b0, { LDB(1, 1, b1); });
    PH(0, 1, b1, { if (more) STG_A(1, t3, 0); LDA(1, 1); });
    PH(1, 1, b1, { if (more) { STG_B(1, t3, 1); VMW(); } });
    PH(1, 0, b0, { if (more) { STG_A(1, t3, 1); STG_B(1, t3, 0);
                               LDA(0, 0); LDB(0, 0, b0); } });
  }
#undef STG_A
#undef STG_B
#undef LDA
#undef LDB
#undef VMW
#undef PH

  // epilogue: 16x16 C/D layout col=lane&15, row=(lane>>4)*4+reg
#pragma unroll
  for (int rh = 0; rh < 2; ++rh)
#pragma unroll
    for (int mq = 0; mq < MQ2; ++mq)
#pragma unroll
      for (int ch = 0; ch < 2; ++ch)
#pragma unroll
        for (int nq = 0; nq < 2; ++nq) {
          const int col = tn + wn * 64 + ch * 32 + nq * 16 + l15;
          const float bv = BIAS ? bias[col] : 0.0f;
          const int row0 = tm + wm * (BM / 2) + rh * (BM / 4) + mq * 16 + g * 4;
#pragma unroll
          for (int r = 0; r < 4; ++r) {
            const float v = acc[rh][mq][ch][nq][r] + bv;
            if (OUTBF) ((short*)outp)[(size_t)(row0 + r) * N + col] = f2bf(v);
            else       ((float*)outp)[(size_t)(row0 + r) * N + col] = v;
          }
        }
}

// ---------------- flash attention, 2-phase pipelined, paired q-tiles --------
__global__ void __launch_bounds__(256) attn_kernel(const short* __restrict__ qkv,
                                                   const short* __restrict__ vtb,
                                                   short* __restrict__ outb) {
  const int lid = (int)blockIdx.x + ((int)blockIdx.y << 4);
  const int kvh = (lid & 7) >> 1;
  const int u = ((lid >> 3) << 1) + (lid & 1);  // 0..111 within kv group
  const int head = kvh * 7 + (u >> 4);
  const int qtA = u & 15, qtB = 31 - qtA;

  const int tid = threadIdx.x;
  const int lane = tid & 63, wave = tid >> 6;
  const int l15 = lane & 15, g = lane >> 4;

  __shared__ short Ks[2][64 * 128];
  __shared__ short Vs[2][128 * 64];
  __shared__ short Ps[4][16 * 64];

  const short* kbase = qkv + 3584 + kvh * 128;
  const short* vbase = vtb + (size_t)kvh * 128 * 2048;
  const float NINF = -__builtin_inff();

  bf16x8 qf[4];
  f32x4 o[8];
  float mrun[4], lrun[4];

#define LOADQ(qt)                                                                  \
  {                                                                                \
    const short* qptr =                                                            \
        qkv + (size_t)((qt)*64 + wave * 16 + l15) * 4608 + head * 128 + g * 8;     \
    _Pragma("unroll") for (int ds = 0; ds < 4; ++ds) qf[ds] =                      \
        *(const bf16x8*)(qptr + ds * 32);                                          \
  }
#define RESET()                                                                    \
  {                                                                                \
    _Pragma("unroll") for (int nd = 0; nd < 8; ++nd) o[nd] = f32x4{0.f,0.f,0.f,0.f}; \
    _Pragma("unroll") for (int r = 0; r < 4; ++r) { mrun[r] = NINF; lrun[r] = 0.f; } \
  }
#define STAGE(kv, b)                                                               \
  {                                                                                \
    _Pragma("unroll") for (int it = 0; it < 4; ++it) {                             \
      const int chunk = it * 256 + tid;                                            \
      const int row = chunk >> 4, sc = (chunk & 15) ^ (row & 7);                   \
      gll16(kbase + (size_t)((kv)*64 + row) * 4608 + sc * 8,                       \
            &Ks[b][(it * 256 + wave * 64) * 8]);                                   \
    }                                                                              \
    _Pragma("unroll") for (int it = 0; it < 4; ++it) {                             \
      const int chunk = it * 256 + tid;                                            \
      const int row = chunk >> 3, sc = (chunk & 7) ^ (row & 7);                    \
      gll16(vbase + (size_t)row * 2048 + (kv)*64 + sc * 8,                         \
            &Vs[b][(it * 256 + wave * 64) * 8]);                                   \
    }                                                                              \
  }

  RESET();
  LOADQ(qtA);
  STAGE(0, 0);
  __syncthreads();
  int cur = 0;

  for (int s = 0; s < 33; ++s) {
    if (s < 32) {
      const int sn = s + 1;
      const int kvn = (sn <= qtA) ? sn : sn - qtA - 1;
      STAGE(kvn, cur ^ 1);
    }
    const int qt = (s <= qtA) ? qtA : qtB;
    const int kv = (s <= qtA) ? s : s - qtA - 1;
    const bool diag = (s == qtA) || (s == 32);

    f32x4 sf[4] = {};
    __builtin_amdgcn_s_setprio(1);
#pragma unroll
    for (int n = 0; n < 4; ++n) {
      const int krow = n * 16 + l15;
#pragma unroll
      for (int ds = 0; ds < 4; ++ds) {
        const int c = (ds * 4 + g) ^ (krow & 7);
        const bf16x8 kf = *(const bf16x8*)(&Ks[cur][krow * 128 + c * 8]);
        sf[n] = MFMA16(qf[ds], kf, sf[n]);
      }
    }
    __builtin_amdgcn_s_setprio(0);

    if (diag) {
#pragma unroll
      for (int r = 0; r < 4; ++r) {
        const int qr = qt * 64 + wave * 16 + g * 4 + r;
#pragma unroll
        for (int n = 0; n < 4; ++n)
          if (kv * 64 + n * 16 + l15 > qr) sf[n][r] = NINF;
      }
    }
    float pmax[4];
#pragma unroll
    for (int r = 0; r < 4; ++r)
      pmax[r] = fmaxf(fmaxf(sf[0][r], sf[1][r]), fmaxf(sf[2][r], sf[3][r]));
    const bool need = (pmax[0] > mrun[0] + 8.f) || (pmax[1] > mrun[1] + 8.f) ||
                      (pmax[2] > mrun[2] + 8.f) || (pmax[3] > mrun[3] + 8.f);
    if (__any(need)) {
#pragma unroll
      for (int r = 0; r < 4; ++r) {
        float mx = pmax[r];
        mx = fmaxf(mx, __shfl_xor(mx, 1));
        mx = fmaxf(mx, __shfl_xor(mx, 2));
        mx = fmaxf(mx, __shfl_xor(mx, 4));
        mx = fmaxf(mx, __shfl_xor(mx, 8));
        const float mnew = fmaxf(mrun[r], mx);
        const float alpha = exp2f(mrun[r] - mnew);
        mrun[r] = mnew;
        lrun[r] *= alpha;
#pragma unroll
        for (int nd = 0; nd < 8; ++nd) o[nd][r] *= alpha;
      }
    }
#pragma unroll
    for (int n = 0; n < 4; ++n) {
#pragma unroll
      for (int r = 0; r < 4; ++r) {
        const float p = exp2f(sf[n][r] - mrun[r]);
        lrun[r] += p;
        const int prow = g * 4 + r, key = n * 16 + l15;
        const int cp = (key >> 3) ^ (prow & 7);
        Ps[wave][prow * 64 + cp * 8 + (key & 7)] = f2bf(p);
      }
    }
    bf16x8 pf[2];
#pragma unroll
    for (int ksl = 0; ksl < 2; ++ksl) {
      const int c = (ksl * 4 + g) ^ (l15 & 7);
      pf[ksl] = *(const bf16x8*)(&Ps[wave][l15 * 64 + c * 8]);
    }
    __builtin_amdgcn_s_setprio(1);
#pragma unroll
    for (int nd = 0; nd < 8; ++nd) {
      const int vrow = nd * 16 + l15;
#pragma unroll
      for (int ksl = 0; ksl < 2; ++ksl) {
        const int c = (ksl * 4 + g) ^ (vrow & 7);
        const bf16x8 vf = *(const bf16x8*)(&Vs[cur][vrow * 64 + c * 8]);
        o[nd] = MFMA16(pf[ksl], vf, o[nd]);
      }
    }
    __builtin_amdgcn_s_setprio(0);

    if (diag) {
      float inv[4];
#pragma unroll
      for (int r = 0; r < 4; ++r) {
        float sum = lrun[r];
        sum += __shfl_xor(sum, 1);
        sum += __shfl_xor(sum, 2);
        sum += __shfl_xor(sum, 4);
        sum += __shfl_xor(sum, 8);
        inv[r] = 1.0f / sum;
      }
#pragma unroll
      for (int nd = 0; nd < 8; ++nd) {
#pragma unroll
        for (int r = 0; r < 4; ++r) {
          const int qr = qt * 64 + wave * 16 + g * 4 + r;
          outb[(size_t)qr * 3584 + head * 128 + nd * 16 + l15] = f2bf(o[nd][r] * inv[r]);
        }
      }
      if (s == qtA) {
        RESET();
        LOADQ(qtB);
      }
    }
    __syncthreads();
    cur ^= 1;
  }
#undef LOADQ
#undef RESET
#undef STAGE
}

extern "C" void kernel_launch(void* const* d_in, const int* in_sizes, int n_in,
                              void* d_out, int out_size, void* d_ws, size_t ws_size,
                              hipStream_t stream) {
  const float* h  = (const float*)d_in[0];
  const int* pos  = (const int*)d_in[1];
  const float* Wq = (const float*)d_in[2];
  const float* bq = (const float*)d_in[3];
  const float* Wk = (const float*)d_in[4];
  const float* bk = (const float*)d_in[5];
  const float* Wv = (const float*)d_in[6];
  const float* bv = (const float*)d_in[7];
  const float* Wo = (const float*)d_in[8];
  float* out = (float*)d_out;

  char* w = (char*)d_ws;
  short* hbf  = (short*)w; w += (size_t)2048 * 3584 * 2;   // 14.7 MB
  short* Wall = (short*)w; w += (size_t)4608 * 3584 * 2;   // 33.0 MB
  short* Wob  = (short*)w; w += (size_t)3584 * 3584 * 2;   // 25.7 MB (separate:
  float* ball = (float*)w; w += 4608 * 4;                  //  written during QKV GEMM)
  short* qkvp = (short*)w; w += (size_t)2048 * 4608 * 2;   // 18.9 MB
  float* ctab = (float*)w; w += 2048 * 64 * 4;
  float* stab = (float*)w; w += 2048 * 64 * 4;
  short* vtb  = (short*)w; w += (size_t)4 * 128 * 2048 * 2;
  short* attnb = hbf;  // hbf dead after QKV GEMM

  cvt4<<<2048, 256, 0, stream>>>(h, Wq, Wk, Wv, hbf, Wall);
  bias_concat<<<18, 256, 0, stream>>>(bq, bk, bv, ball);
  rope_table<<<2048, 64, 0, stream>>>(pos, ctab, stab);

  // QKV GEMM on blocks 0..143 (2x9 XCD rects, lockstep L2 sharing) +
  // Wo f32->bf16 conversion on blocks 144..255 (otherwise-idle CUs).
  gemm10<256, 18, 2, 9, true, true, true><<<256, 512, 0, stream>>>(
      hbf, Wall, ball, qkvp, 4608, 3584, Wo, Wob);

  rope_apply<<<2048, 256, 0, stream>>>(qkvp, ctab, stab);
  v_transpose<<<dim3(4, 32, 4), 256, 0, stream>>>(qkvp, vtb);

  attn_kernel<<<dim3(16, 28), 256, 0, stream>>>(qkvp, vtb, attnb);

  gemm10<128, 14, 4, 7, false, false, false><<<224, 512, 0, stream>>>(
      attnb, Wob, nullptr, out, 3584, 3584, nullptr, nullptr);
}

// Round 14
// 224.023 us; speedup vs baseline: 2.2729x; 1.0541x over previous
//
#include <hip/hip_runtime.h>

typedef __attribute__((ext_vector_type(4))) float f32x4;
typedef __attribute__((ext_vector_type(8))) short bf16x8;

#define MFMA16(a, b, c) __builtin_amdgcn_mfma_f32_16x16x32_bf16((a), (b), (c), 0, 0, 0)
#define LOG2E 1.44269504088896340736f

static __device__ __forceinline__ float bf2f(short u) {
  unsigned x = ((unsigned)(unsigned short)u) << 16;
  return __builtin_bit_cast(float, x);
}
static __device__ __forceinline__ short f2bf(float f) {
  unsigned u = __builtin_bit_cast(unsigned, f);
  u += 0x7fffu + ((u >> 16) & 1u);
  return (short)(u >> 16);
}
// global -> LDS direct DMA, 16B per lane (guide §5); source pre-swizzled.
static __device__ __forceinline__ void gll16(const void* g, void* l) {
  __builtin_amdgcn_global_load_lds(
      (const __attribute__((address_space(1))) unsigned*)(unsigned long long)g,
      (__attribute__((address_space(3))) unsigned*)(unsigned)(unsigned long long)l,
      16, 0, 0);
}

// --- merged setup: f32->bf16 cvt (h,Wq,Wk,Wv) + rope table + bias concat ---
// blocks 0..2047: grid-stride conversion; blocks 2048..2303: rope cos/sin
// table (2 entries/thread); blocks 2048..2065 additionally: bias concat.
__global__ void __launch_bounds__(256) setup_all(const float* __restrict__ h,
                                                 const float* __restrict__ wq,
                                                 const float* __restrict__ wk,
                                                 const float* __restrict__ wv,
                                                 short* __restrict__ hbf,
                                                 short* __restrict__ wall,
                                                 const int* __restrict__ pos,
                                                 float* __restrict__ ctab,
                                                 float* __restrict__ stab,
                                                 const float* __restrict__ bq,
                                                 const float* __restrict__ bk,
                                                 const float* __restrict__ bv,
                                                 float* __restrict__ ball) {
  const int bid = (int)blockIdx.x;
  const int tid = (int)threadIdx.x;
  if (bid >= 2048) {
    const int rb = bid - 2048;  // 0..255
    if (rb < 18) {
      const int i = rb * 256 + tid;
      if (i < 3584) ball[i] = bq[i];
      else if (i < 4096) ball[i] = bk[i - 3584];
      else if (i < 4608) ball[i] = bv[i - 4096];
    }
#pragma unroll
    for (int e = 0; e < 2; ++e) {
      const int ii = (rb * 256 + tid) * 2 + e;  // 0..131071
      const int s = ii >> 6, i = ii & 63;
      const float p = (float)pos[s];
      const float ang = p * exp2f(-(float)i * 0.3114307588956902f);
      ctab[s * 64 + i] = cosf(ang);
      stab[s * 64 + i] = sinf(ang);
    }
    return;
  }
  const long long C0 = 917504, C1 = 1605632, C2 = 229376;  // 8-elem chunks
  long long ch = (long long)bid * 256 + tid;
  const long long stride = (long long)2048 * 256;
  const long long total = C0 + C1 + 2 * C2;
  for (; ch < total; ch += stride) {
    const float* s;
    short* d;
    long long off;
    if (ch < C0) { s = h; d = hbf; off = ch; }
    else if (ch < C0 + C1) { s = wq; d = wall; off = ch - C0; }
    else if (ch < C0 + C1 + C2) { s = wk; d = wall + (size_t)3584 * 3584; off = ch - C0 - C1; }
    else { s = wv; d = wall + (size_t)4096 * 3584; off = ch - C0 - C1 - C2; }
    const long long i = off * 8;
    f32x4 a = *(const f32x4*)(s + i);
    f32x4 b = *(const f32x4*)(s + i + 4);
    bf16x8 o;
    o[0] = f2bf(a[0]); o[1] = f2bf(a[1]); o[2] = f2bf(a[2]); o[3] = f2bf(a[3]);
    o[4] = f2bf(b[0]); o[5] = f2bf(b[1]); o[6] = f2bf(b[2]); o[7] = f2bf(b[3]);
    *(bf16x8*)(d + i) = o;
  }
}

// --- fused RoPE (in-place on qkv q/k regions) + V transpose -> vtb ---------
// blocks 0..2047: rope; blocks 2048..2559: v_transpose (dt,st,kv unpacked).
// Q heads (h<28) pre-scaled by SCALE*LOG2E (exp2-domain scores).
__global__ void __launch_bounds__(256) rope_vt(short* __restrict__ qkv,
                                               const float* __restrict__ ctab,
                                               const float* __restrict__ stab,
                                               short* __restrict__ vtb) {
  const int bid = (int)blockIdx.x;
  const int tid = (int)threadIdx.x;
  if (bid >= 2048) {
    __shared__ short t[64 * 48];
    const int vb = bid - 2048;  // 0..511
    const int dt = vb & 3, st = (vb >> 2) & 31, kv = vb >> 7;
    {
      const int r = tid >> 2, c8 = tid & 3;
      const bf16x8 v = *(const bf16x8*)(qkv + (size_t)(st * 64 + r) * 4608 + 4096 +
                                        kv * 128 + dt * 32 + c8 * 8);
      *(bf16x8*)(t + r * 48 + c8 * 8) = v;
    }
    __syncthreads();
    {
      const int d = tid >> 3, c = tid & 7;
      bf16x8 v;
#pragma unroll
      for (int i = 0; i < 8; ++i) v[i] = t[(c * 8 + i) * 48 + d];
      *(bf16x8*)(vtb + ((size_t)kv * 128 + dt * 32 + d) * 2048 + st * 64 + c * 8) = v;
    }
    return;
  }
  const int idx = bid * 256 + tid;  // 2048*32*8
  const int c = idx & 7;
  const int h = (idx >> 3) & 31;
  const int s = idx >> 8;
  const float qs = (h < 28) ? (0.08838834764831845f * LOG2E) : 1.0f;
  short* base = qkv + (size_t)s * 4608 + h * 128 + c * 8;
  bf16x8 lo = *(bf16x8*)base;
  bf16x8 hi = *(bf16x8*)(base + 64);
  const float* cp = ctab + s * 64 + c * 8;
  const float* sp = stab + s * 64 + c * 8;
  bf16x8 lo2, hi2;
#pragma unroll
  for (int j = 0; j < 8; ++j) {
    const float x = bf2f(lo[j]), y = bf2f(hi[j]);
    const float cv = cp[j], sv = sp[j];
    lo2[j] = f2bf((x * cv - y * sv) * qs);
    hi2[j] = f2bf((y * cv + x * sv) * qs);
  }
  *(bf16x8*)base = lo2;
  *(bf16x8*)(base + 64) = hi2;
}

// --- 8-phase bf16 GEMM, read-ahead tails (r7-proven, ~88 us) ----------------
// C[M=2048,N] = A[M,K]*B[N,K]^T (+bias). BMx256 tile, 8 waves (2M x 4N),
// BK=64, 2 K-tiles/iter double-buffered. Phase = {bar; lgkmcnt(0);
// sched_barrier; 16 MFMA setprio'd; tail: STG -> [VMW] -> READ next frags}.
// Lockstep per-tile blocks -> same-instant L2 sharing (FETCH ~104 MB; all
// stream-K variants regressed). 2D XCD chunking: xcd=bid&7 owns an MCHxNCH
// tile rect. HETERO: blocks with idx >= MCH*NCH convert Wo instead.
template <int BM, int NT, int MCH, int NCH, bool BIAS, bool OUTBF, bool HETERO>
__global__ void __launch_bounds__(512, 2)
gemm10(const short* __restrict__ A, const short* __restrict__ B,
       const float* __restrict__ bias, void* __restrict__ outp, int N, int K,
       const float* __restrict__ xsrc, short* __restrict__ xdst) {
  constexpr int MQ2 = BM / 64;     // m-frags per rh-half (256->4, 128->2)
  constexpr int ACH = BM / 128;    // gll16 calls per A half-tile
  __shared__ short As[2][BM * 64];
  __shared__ short Bs[2][256 * 64];
  const int bid = (int)blockIdx.x;
  const int tid = (int)threadIdx.x;
  if (HETERO && (bid >> 3) >= MCH * NCH) {
    // cvt role: blocks 144..255 convert Wo (f32 -> bf16), grid-stride.
    const int cb = bid - 8 * MCH * NCH;  // 0..111
    long long i = ((long long)cb * 512 + tid) * 8;
    const long long stride = (long long)112 * 512 * 8;
    const long long n = (long long)3584 * 3584;
    for (; i < n; i += stride) {
      f32x4 a = *(const f32x4*)(xsrc + i);
      f32x4 b = *(const f32x4*)(xsrc + i + 4);
      bf16x8 o;
      o[0] = f2bf(a[0]); o[1] = f2bf(a[1]); o[2] = f2bf(a[2]); o[3] = f2bf(a[3]);
      o[4] = f2bf(b[0]); o[5] = f2bf(b[1]); o[6] = f2bf(b[2]); o[7] = f2bf(b[3]);
      *(bf16x8*)(xdst + i) = o;
    }
    return;
  }
  const int xcd = bid & 7, idx = bid >> 3;
  const int rowg = xcd / (NT / NCH), colg = xcd % (NT / NCH);
  const int tm = (rowg * MCH + idx % MCH) * BM;
  const int tn = (colg * NCH + idx / MCH) * 256;
  const int wave = tid >> 6, lane = tid & 63;
  const int l15 = lane & 15, g = lane >> 4;
  const int wm = wave >> 2, wn = wave & 3;

  f32x4 acc[2][MQ2][2][2] = {};  // [rh][mq][ch][nq]
  bf16x8 af[MQ2][2], b0[2][2], b1[2][2];

#define STG_A(b, kt, h)                                                         \
  { _Pragma("unroll") for (int j = 0; j < ACH; ++j) {                           \
      const int lr = (h) * (BM / 2) + j * 64 + (tid >> 3);                      \
      const int wmm = (lr / (BM / 4)) & 1;                                      \
      const int rr = lr & (BM / 4 - 1);                                         \
      const int grow = wmm * (BM / 2) + (h) * (BM / 4) + rr;                    \
      const int sc = (tid & 7) ^ (rr & 7);                                      \
      gll16(A + (size_t)(tm + grow) * K + (size_t)(kt) * 64 + sc * 8,           \
            &As[b][((h) * (BM / 2) + j * 64 + wave * 8) * 64]);                 \
    } }
#define STG_B(b, kt, h)                                                         \
  { _Pragma("unroll") for (int j = 0; j < 2; ++j) {                             \
      const int lr = (h) * 128 + j * 64 + (tid >> 3);                           \
      const int wnn = (lr >> 5) & 3;                                            \
      const int rr = lr & 31;                                                   \
      const int gcol = wnn * 64 + (h) * 32 + rr;                                \
      const int sc = (tid & 7) ^ (rr & 7);                                      \
      gll16(B + (size_t)(tn + gcol) * K + (size_t)(kt) * 64 + sc * 8,           \
            &Bs[b][((h) * 128 + j * 64 + wave * 8) * 64]);                      \
    } }
#define LDA(buf, rh)                                                            \
  { _Pragma("unroll") for (int mq = 0; mq < MQ2; ++mq)                          \
      _Pragma("unroll") for (int ks = 0; ks < 2; ++ks) {                        \
        const int lr = (rh) * (BM / 2) + wm * (BM / 4) + mq * 16 + l15;         \
        af[mq][ks] =                                                            \
            *(const bf16x8*)(&As[buf][lr * 64 + (((ks * 4 + g) ^ (lr & 7)) * 8)]); \
      } }
#define LDB(buf, ch, ARR)                                                       \
  { _Pragma("unroll") for (int nq = 0; nq < 2; ++nq)                            \
      _Pragma("unroll") for (int ks = 0; ks < 2; ++ks) {                        \
        const int lr = (ch) * 128 + wn * 32 + nq * 16 + l15;                    \
        ARR[nq][ks] =                                                           \
            *(const bf16x8*)(&Bs[buf][lr * 64 + (((ks * 4 + g) ^ (lr & 7)) * 8)]); \
      } }
#define VMW()                                                                   \
  { if constexpr (ACH == 2) { asm volatile("s_waitcnt vmcnt(4)" ::: "memory"); }\
    else { asm volatile("s_waitcnt vmcnt(3)" ::: "memory"); } }
#define PH(RH, CH, BARR, TAILBLK)                                               \
  {                                                                             \
    __builtin_amdgcn_s_barrier();                                               \
    asm volatile("s_waitcnt lgkmcnt(0)" ::: "memory");                          \
    __builtin_amdgcn_sched_barrier(0);                                          \
    __builtin_amdgcn_s_setprio(1);                                              \
    _Pragma("unroll") for (int mq = 0; mq < MQ2; ++mq)                          \
      _Pragma("unroll") for (int nq = 0; nq < 2; ++nq) {                        \
        acc[RH][mq][CH][nq] = MFMA16(af[mq][0], BARR[nq][0], acc[RH][mq][CH][nq]); \
        acc[RH][mq][CH][nq] = MFMA16(af[mq][1], BARR[nq][1], acc[RH][mq][CH][nq]); \
      }                                                                         \
    __builtin_amdgcn_s_setprio(0);                                              \
    TAILBLK;                                                                    \
    __builtin_amdgcn_sched_barrier(0);                                          \
  }

  // prologue: stage t0+t1; wait t0 landed; barrier; read P1's frags.
  STG_A(0, 0, 0); STG_A(0, 0, 1); STG_B(0, 0, 0); STG_B(0, 0, 1);
  STG_A(1, 1, 0); STG_A(1, 1, 1); STG_B(1, 1, 0); STG_B(1, 1, 1);
  if constexpr (ACH == 2) { asm volatile("s_waitcnt vmcnt(8)" ::: "memory"); }
  else                    { asm volatile("s_waitcnt vmcnt(6)" ::: "memory"); }
  __builtin_amdgcn_s_barrier();
  LDA(0, 0); LDB(0, 0, b0);

  const int L = K >> 7;  // 28 iterations, 2 K-tiles each
  for (int i = 0; i < L; ++i) {
    const int t2 = 2 * i + 2, t3 = 2 * i + 3;
    const bool more = (i < L - 1);
    PH(0, 0, b0, { LDB(0, 1, b1); });
    PH(0, 1, b1, { if (more) STG_A(0, t2, 0); LDA(0, 1); });
    PH(1, 1, b1, { if (more) { STG_B(0, t2, 1); VMW(); }
                   else { asm volatile("s_waitcnt vmcnt(0)" ::: "memory"); } });
    PH(1, 0, b0, { if (more) { STG_A(0, t2, 1); STG_B(0, t2, 0); }
                   LDA(1, 0); LDB(1, 0, b0); });
    PH(0, 0, b0, { LDB(1, 1, b1); });
    PH(0, 1, b1, { if (more) STG_A(1, t3, 0); LDA(1, 1); });
    PH(1, 1, b1, { if (more) { STG_B(1, t3, 1); VMW(); } });
    PH(1, 0, b0, { if (more) { STG_A(1, t3, 1); STG_B(1, t3, 0);
                               LDA(0, 0); LDB(0, 0, b0); } });
  }
#undef STG_A
#undef STG_B
#undef LDA
#undef LDB
#undef VMW
#undef PH

  // epilogue: 16x16 C/D layout col=lane&15, row=(lane>>4)*4+reg
#pragma unroll
  for (int rh = 0; rh < 2; ++rh)
#pragma unroll
    for (int mq = 0; mq < MQ2; ++mq)
#pragma unroll
      for (int ch = 0; ch < 2; ++ch)
#pragma unroll
        for (int nq = 0; nq < 2; ++nq) {
          const int col = tn + wn * 64 + ch * 32 + nq * 16 + l15;
          const float bv = BIAS ? bias[col] : 0.0f;
          const int row0 = tm + wm * (BM / 2) + rh * (BM / 4) + mq * 16 + g * 4;
#pragma unroll
          for (int r = 0; r < 4; ++r) {
            const float v = acc[rh][mq][ch][nq][r] + bv;
            if (OUTBF) ((short*)outp)[(size_t)(row0 + r) * N + col] = f2bf(v);
            else       ((float*)outp)[(size_t)(row0 + r) * N + col] = v;
          }
        }
}

// ------- flash attention, 2-phase pipelined, 896 blocks (longest-first) -----
// r9-proven singleton variant: block work proportional to qt+1; dispatch
// order longest-first -> greedy balance across 256 CUs (~3.5 blocks/CU).
__global__ void __launch_bounds__(256) attn_kernel(const short* __restrict__ qkv,
                                                   const short* __restrict__ vtb,
                                                   short* __restrict__ outb) {
  const int lid = (int)blockIdx.x;   // 0..895, dispatched in order
  const int head = lid % 28;
  const int qt = 31 - lid / 28;      // longest q-tiles first
  const int kvh = head / 7;

  const int tid = threadIdx.x;
  const int lane = tid & 63, wave = tid >> 6;
  const int l15 = lane & 15, g = lane >> 4;

  __shared__ short Ks[2][64 * 128];
  __shared__ short Vs[2][128 * 64];
  __shared__ short Ps[4][16 * 64];

  const short* kbase = qkv + 3584 + kvh * 128;
  const short* vbase = vtb + (size_t)kvh * 128 * 2048;
  const float NINF = -__builtin_inff();

  bf16x8 qf[4];
  {
    const short* qptr = qkv + (size_t)(qt * 64 + wave * 16 + l15) * 4608 + head * 128 + g * 8;
#pragma unroll
    for (int ds = 0; ds < 4; ++ds) qf[ds] = *(const bf16x8*)(qptr + ds * 32);
  }
  f32x4 o[8] = {};
  float mrun[4] = {NINF, NINF, NINF, NINF};
  float lrun[4] = {0.f, 0.f, 0.f, 0.f};

#define STAGE(kv, b)                                                               \
  {                                                                                \
    _Pragma("unroll") for (int it = 0; it < 4; ++it) {                             \
      const int chunk = it * 256 + tid;                                            \
      const int row = chunk >> 4, sc = (chunk & 15) ^ (row & 7);                   \
      gll16(kbase + (size_t)((kv)*64 + row) * 4608 + sc * 8,                       \
            &Ks[b][(it * 256 + wave * 64) * 8]);                                   \
    }                                                                              \
    _Pragma("unroll") for (int it = 0; it < 4; ++it) {                             \
      const int chunk = it * 256 + tid;                                            \
      const int row = chunk >> 3, sc = (chunk & 7) ^ (row & 7);                    \
      gll16(vbase + (size_t)row * 2048 + (kv)*64 + sc * 8,                         \
            &Vs[b][(it * 256 + wave * 64) * 8]);                                   \
    }                                                                              \
  }

  STAGE(0, 0);
  __syncthreads();
  int cur = 0;

#pragma unroll 1
  for (int t = 0; t <= qt; ++t) {
    if (t < qt) STAGE(t + 1, cur ^ 1);
    const bool diag = (t == qt);

    f32x4 sf[4] = {};
    __builtin_amdgcn_s_setprio(1);
#pragma unroll
    for (int n = 0; n < 4; ++n) {
      const int krow = n * 16 + l15;
#pragma unroll
      for (int ds = 0; ds < 4; ++ds) {
        const int c = (ds * 4 + g) ^ (krow & 7);
        const bf16x8 kf = *(const bf16x8*)(&Ks[cur][krow * 128 + c * 8]);
        sf[n] = MFMA16(qf[ds], kf, sf[n]);
      }
    }
    __builtin_amdgcn_s_setprio(0);

    if (diag) {
#pragma unroll
      for (int r = 0; r < 4; ++r) {
        const int qr = qt * 64 + wave * 16 + g * 4 + r;
#pragma unroll
        for (int n = 0; n < 4; ++n)
          if (t * 64 + n * 16 + l15 > qr) sf[n][r] = NINF;
      }
    }
    float pmax[4];
#pragma unroll
    for (int r = 0; r < 4; ++r)
      pmax[r] = fmaxf(fmaxf(sf[0][r], sf[1][r]), fmaxf(sf[2][r], sf[3][r]));
    const bool need = (pmax[0] > mrun[0] + 8.f) || (pmax[1] > mrun[1] + 8.f) ||
                      (pmax[2] > mrun[2] + 8.f) || (pmax[3] > mrun[3] + 8.f);
    if (__any(need)) {
#pragma unroll
      for (int r = 0; r < 4; ++r) {
        float mx = pmax[r];
        mx = fmaxf(mx, __shfl_xor(mx, 1));
        mx = fmaxf(mx, __shfl_xor(mx, 2));
        mx = fmaxf(mx, __shfl_xor(mx, 4));
        mx = fmaxf(mx, __shfl_xor(mx, 8));
        const float mnew = fmaxf(mrun[r], mx);
        const float alpha = exp2f(mrun[r] - mnew);
        mrun[r] = mnew;
        lrun[r] *= alpha;
#pragma unroll
        for (int nd = 0; nd < 8; ++nd) o[nd][r] *= alpha;
      }
    }
#pragma unroll
    for (int n = 0; n < 4; ++n) {
#pragma unroll
      for (int r = 0; r < 4; ++r) {
        const float p = exp2f(sf[n][r] - mrun[r]);
        lrun[r] += p;
        const int prow = g * 4 + r, key = n * 16 + l15;
        const int cp = (key >> 3) ^ (prow & 7);
        Ps[wave][prow * 64 + cp * 8 + (key & 7)] = f2bf(p);
      }
    }
    bf16x8 pf[2];
#pragma unroll
    for (int ksl = 0; ksl < 2; ++ksl) {
      const int c = (ksl * 4 + g) ^ (l15 & 7);
      pf[ksl] = *(const bf16x8*)(&Ps[wave][l15 * 64 + c * 8]);
    }
    __builtin_amdgcn_s_setprio(1);
#pragma unroll
    for (int nd = 0; nd < 8; ++nd) {
      const int vrow = nd * 16 + l15;
#pragma unroll
      for (int ksl = 0; ksl < 2; ++ksl) {
        const int c = (ksl * 4 + g) ^ (vrow & 7);
        const bf16x8 vf = *(const bf16x8*)(&Vs[cur][vrow * 64 + c * 8]);
        o[nd] = MFMA16(pf[ksl], vf, o[nd]);
      }
    }
    __builtin_amdgcn_s_setprio(0);

    __syncthreads();
    cur ^= 1;
  }

  float inv[4];
#pragma unroll
  for (int r = 0; r < 4; ++r) {
    float sum = lrun[r];
    sum += __shfl_xor(sum, 1);
    sum += __shfl_xor(sum, 2);
    sum += __shfl_xor(sum, 4);
    sum += __shfl_xor(sum, 8);
    inv[r] = 1.0f / sum;
  }
#pragma unroll
  for (int nd = 0; nd < 8; ++nd) {
#pragma unroll
    for (int r = 0; r < 4; ++r) {
      const int qr = qt * 64 + wave * 16 + g * 4 + r;
      outb[(size_t)qr * 3584 + head * 128 + nd * 16 + l15] = f2bf(o[nd][r] * inv[r]);
    }
  }
#undef STAGE
}

extern "C" void kernel_launch(void* const* d_in, const int* in_sizes, int n_in,
                              void* d_out, int out_size, void* d_ws, size_t ws_size,
                              hipStream_t stream) {
  const float* h  = (const float*)d_in[0];
  const int* pos  = (const int*)d_in[1];
  const float* Wq = (const float*)d_in[2];
  const float* bq = (const float*)d_in[3];
  const float* Wk = (const float*)d_in[4];
  const float* bk = (const float*)d_in[5];
  const float* Wv = (const float*)d_in[6];
  const float* bv = (const float*)d_in[7];
  const float* Wo = (const float*)d_in[8];
  float* out = (float*)d_out;

  char* w = (char*)d_ws;
  short* hbf  = (short*)w; w += (size_t)2048 * 3584 * 2;   // 14.7 MB
  short* Wall = (short*)w; w += (size_t)4608 * 3584 * 2;   // 33.0 MB
  short* Wob  = (short*)w; w += (size_t)3584 * 3584 * 2;   // 25.7 MB
  float* ball = (float*)w; w += 4608 * 4;
  short* qkvp = (short*)w; w += (size_t)2048 * 4608 * 2;   // 18.9 MB
  float* ctab = (float*)w; w += 2048 * 64 * 4;
  float* stab = (float*)w; w += 2048 * 64 * 4;
  short* vtb  = (short*)w; w += (size_t)4 * 128 * 2048 * 2;
  short* attnb = hbf;  // hbf dead after QKV GEMM

  // cvt (h,Wq,Wk,Wv) + rope table + bias concat, one launch
  setup_all<<<2304, 256, 0, stream>>>(h, Wq, Wk, Wv, hbf, Wall, pos, ctab, stab,
                                      bq, bk, bv, ball);

  // QKV GEMM on blocks 0..143 (2x9 XCD rects, lockstep L2 sharing) +
  // Wo f32->bf16 conversion on blocks 144..255 (otherwise-idle CUs).
  gemm10<256, 18, 2, 9, true, true, true><<<256, 512, 0, stream>>>(
      hbf, Wall, ball, qkvp, 4608, 3584, Wo, Wob);

  // RoPE (q,k) + V transpose, one launch
  rope_vt<<<2560, 256, 0, stream>>>(qkvp, ctab, stab, vtb);

  attn_kernel<<<896, 256, 0, stream>>>(qkvp, vtb, attnb);

  gemm10<128, 14, 4, 7, false, false, false><<<224, 512, 0, stream>>>(
      attnb, Wob, nullptr, out, 3584, 3584, nullptr, nullptr);
}